// Round 1
// baseline (2294.754 us; speedup 1.0000x reference)
//
#include <hip/hip_runtime.h>
#include <math.h>

#define BB 2
#define SS 4096
#define DD 768
#define HH 12
#define LL 2
#define FF 3072
#define CC 256
#define MM 8192   // B*S

using frag8 = __attribute__((ext_vector_type(8))) short;   // 8 bf16
using f32x4 = __attribute__((ext_vector_type(4))) float;

// ---------- helpers ----------
__device__ __forceinline__ unsigned short f2b(float f) {
  unsigned u = __float_as_uint(f);
  u = u + 0x7fffu + ((u >> 16) & 1u);   // RNE
  return (unsigned short)(u >> 16);
}
__device__ __forceinline__ unsigned pack2(float a, float b) {
  return (unsigned)f2b(a) | ((unsigned)f2b(b) << 16);
}
__device__ __forceinline__ void unpack8(int4 t, float* f) {
  unsigned u;
  u = (unsigned)t.x; f[0] = __uint_as_float(u << 16); f[1] = __uint_as_float(u & 0xffff0000u);
  u = (unsigned)t.y; f[2] = __uint_as_float(u << 16); f[3] = __uint_as_float(u & 0xffff0000u);
  u = (unsigned)t.z; f[4] = __uint_as_float(u << 16); f[5] = __uint_as_float(u & 0xffff0000u);
  u = (unsigned)t.w; f[6] = __uint_as_float(u << 16); f[7] = __uint_as_float(u & 0xffff0000u);
}
__device__ __forceinline__ void load64(const unsigned short* p, float* q) {
#pragma unroll
  for (int i = 0; i < 8; i++) {
    int4 t = *reinterpret_cast<const int4*>(p + i * 8);
    unpack8(t, q + i * 8);
  }
}
__device__ __forceinline__ float dot64(const float* q, const unsigned short* p) {
  float s = 0.f;
#pragma unroll
  for (int i = 0; i < 8; i++) {
    int4 t = *reinterpret_cast<const int4*>(p + i * 8);
    float f[8]; unpack8(t, f);
#pragma unroll
    for (int j = 0; j < 8; j++) s = fmaf(q[i * 8 + j], f[j], s);
  }
  return s;
}
__device__ __forceinline__ void axpy64g(float pw, const unsigned short* vp, float* o) {
#pragma unroll
  for (int i = 0; i < 8; i++) {
    int4 t = *reinterpret_cast<const int4*>(vp + i * 8);
    float f[8]; unpack8(t, f);
#pragma unroll
    for (int j = 0; j < 8; j++) o[i * 8 + j] = fmaf(pw, f[j], o[i * 8 + j]);
  }
}
__device__ __forceinline__ void reduce2(float& s1, float& s2) {
#pragma unroll
  for (int off = 32; off > 0; off >>= 1) {
    s1 += __shfl_down(s1, off);
    s2 += __shfl_down(s2, off);
  }
  __shared__ float r1[4], r2[4];
  const int lane = threadIdx.x & 63, wv = threadIdx.x >> 6;
  if (lane == 0) { r1[wv] = s1; r2[wv] = s2; }
  __syncthreads();
  s1 = r1[0] + r1[1] + r1[2] + r1[3];
  s2 = r2[0] + r2[1] + r2[2] + r2[3];
  __syncthreads();
}

// ---------- weight transpose fp32(K,N) -> bf16(N,K) ----------
__global__ __launch_bounds__(256) void transpose_bf16(const float* __restrict__ in,
                                                      unsigned short* __restrict__ out,
                                                      int K, int N) {
  __shared__ float t[32][33];
  const int n0 = blockIdx.x * 32, k0 = blockIdx.y * 32;
  const int tx = threadIdx.x, ty = threadIdx.y;   // block (32,8)
#pragma unroll
  for (int i = 0; i < 32; i += 8) t[ty + i][tx] = in[(size_t)(k0 + ty + i) * N + n0 + tx];
  __syncthreads();
#pragma unroll
  for (int i = 0; i < 32; i += 8) out[(size_t)(n0 + ty + i) * K + k0 + tx] = f2b(t[tx][ty + i]);
}

// ---------- embedding + LN ----------
__global__ __launch_bounds__(256) void embed_ln(const int* __restrict__ ids,
                                                const float* __restrict__ etok,
                                                const float* __restrict__ epos,
                                                const float* __restrict__ g,
                                                const float* __restrict__ bb,
                                                float* __restrict__ h32,
                                                unsigned short* __restrict__ hB) {
  const int row = blockIdx.x;
  const int s = row & (SS - 1);
  const int id = ids[row];
  float x[3];
#pragma unroll
  for (int i = 0; i < 3; i++) {
    int j = threadIdx.x + i * 256;
    x[i] = etok[(size_t)id * DD + j] + epos[(size_t)s * DD + j];
  }
  float s1 = x[0] + x[1] + x[2];
  float s2 = x[0] * x[0] + x[1] * x[1] + x[2] * x[2];
  reduce2(s1, s2);
  const float mean = s1 * (1.f / 768.f);
  const float var = s2 * (1.f / 768.f) - mean * mean;
  const float rs = rsqrtf(var + 1e-5f);
#pragma unroll
  for (int i = 0; i < 3; i++) {
    int j = threadIdx.x + i * 256;
    float y = (x[i] - mean) * rs * g[j] + bb[j];
    h32[(size_t)row * DD + j] = y;
    hB[(size_t)row * DD + j] = f2b(y);
  }
}

// ---------- residual + LN ----------
__global__ __launch_bounds__(256) void ln_res(float* __restrict__ h32,
                                              const float* __restrict__ delta,
                                              const float* __restrict__ g,
                                              const float* __restrict__ bb,
                                              unsigned short* __restrict__ hB) {
  const int row = blockIdx.x;
  float x[3];
#pragma unroll
  for (int i = 0; i < 3; i++) {
    int j = threadIdx.x + i * 256;
    x[i] = h32[(size_t)row * DD + j] + delta[(size_t)row * DD + j];
  }
  float s1 = x[0] + x[1] + x[2];
  float s2 = x[0] * x[0] + x[1] * x[1] + x[2] * x[2];
  reduce2(s1, s2);
  const float mean = s1 * (1.f / 768.f);
  const float var = s2 * (1.f / 768.f) - mean * mean;
  const float rs = rsqrtf(var + 1e-5f);
#pragma unroll
  for (int i = 0; i < 3; i++) {
    int j = threadIdx.x + i * 256;
    float y = (x[i] - mean) * rs * g[j] + bb[j];
    h32[(size_t)row * DD + j] = y;
    hB[(size_t)row * DD + j] = f2b(y);
  }
}

// ---------- bf16 MFMA GEMM:  C(M,N) = A(M,K) @ Bt(N,K)^T + bias ----------
// EPI 0: fp32 row-major (outF, bias0)
// EPI 1: fused QKV scatter -> (B,H,S,DH) bf16, q scaled 0.125 (N=2304)
// EPI 2: GELU -> bf16 row-major (oq, bias0)
template <int EPI>
__global__ __launch_bounds__(256) void gemm_nt(const unsigned short* __restrict__ A,
                                               const unsigned short* __restrict__ Bt,
                                               const float* __restrict__ bias0,
                                               const float* __restrict__ bias1,
                                               const float* __restrict__ bias2,
                                               float* __restrict__ outF,
                                               unsigned short* __restrict__ oq,
                                               unsigned short* __restrict__ ok,
                                               unsigned short* __restrict__ ov,
                                               int M, int N, int K) {
  __shared__ unsigned short sA[128 * 32];
  __shared__ unsigned short sB[128 * 32];
  const int tid = threadIdx.x;
  const int m0 = blockIdx.y * 128, n0 = blockIdx.x * 128;
  const int wave = tid >> 6, lane = tid & 63;
  const int wm = (wave >> 1) * 64, wn = (wave & 1) * 64;
  const int quad = lane >> 4, r16 = lane & 15;
  const int rowA = tid >> 2;
  const int colA = (tid & 3) * 8;

  f32x4 acc[4][4];
#pragma unroll
  for (int i = 0; i < 4; i++)
#pragma unroll
    for (int j = 0; j < 4; j++) acc[i][j] = (f32x4){0.f, 0.f, 0.f, 0.f};

  const int kiters = K >> 5;
  for (int kt = 0; kt < kiters; kt++) {
    const int k0 = kt << 5;
    int4 a0 = *reinterpret_cast<const int4*>(A + (size_t)(m0 + rowA) * K + k0 + colA);
    int4 a1 = *reinterpret_cast<const int4*>(A + (size_t)(m0 + 64 + rowA) * K + k0 + colA);
    int4 b0 = *reinterpret_cast<const int4*>(Bt + (size_t)(n0 + rowA) * K + k0 + colA);
    int4 b1 = *reinterpret_cast<const int4*>(Bt + (size_t)(n0 + 64 + rowA) * K + k0 + colA);
    __syncthreads();
    *reinterpret_cast<int4*>(&sA[rowA * 32 + colA]) = a0;
    *reinterpret_cast<int4*>(&sA[(64 + rowA) * 32 + colA]) = a1;
    *reinterpret_cast<int4*>(&sB[rowA * 32 + colA]) = b0;
    *reinterpret_cast<int4*>(&sB[(64 + rowA) * 32 + colA]) = b1;
    __syncthreads();
    frag8 af[4], bf[4];
#pragma unroll
    for (int i = 0; i < 4; i++)
      af[i] = *reinterpret_cast<const frag8*>(&sA[(wm + i * 16 + r16) * 32 + quad * 8]);
#pragma unroll
    for (int j = 0; j < 4; j++)
      bf[j] = *reinterpret_cast<const frag8*>(&sB[(wn + j * 16 + r16) * 32 + quad * 8]);
#pragma unroll
    for (int i = 0; i < 4; i++)
#pragma unroll
      for (int j = 0; j < 4; j++)
        acc[i][j] = __builtin_amdgcn_mfma_f32_16x16x32_bf16(af[i], bf[j], acc[i][j], 0, 0, 0);
  }

#pragma unroll
  for (int i = 0; i < 4; i++)
#pragma unroll
    for (int j = 0; j < 4; j++)
#pragma unroll
      for (int rr = 0; rr < 4; rr++) {
        const int row = m0 + wm + i * 16 + quad * 4 + rr;
        const int col = n0 + wn + j * 16 + r16;
        if (EPI == 0) {
          outF[(size_t)row * N + col] = acc[i][j][rr] + bias0[col];
        } else if (EPI == 1) {
          const int which = col / 768;
          const int hd = col - which * 768;
          const float bsv = (which == 0) ? bias0[hd] : (which == 1) ? bias1[hd] : bias2[hd];
          float v = acc[i][j][rr] + bsv;
          if (which == 0) v *= 0.125f;
          unsigned short* dst = (which == 0) ? oq : (which == 1) ? ok : ov;
          const int bq = row >> 12, sq = row & (SS - 1);
          dst[((size_t)(bq * HH + (hd >> 6)) * SS + sq) * 64 + (hd & 63)] = f2b(v);
        } else {
          float v = acc[i][j][rr] + bias0[col];
          float ge = 0.5f * v * (1.f + erff(v * 0.70710678118654752f));
          oq[(size_t)row * N + col] = f2b(ge);
        }
      }
}

// ---------- sliding-window attention (one thread = one query row) ----------
__global__ __launch_bounds__(256) void attn_win(const unsigned short* __restrict__ qB,
                                                const unsigned short* __restrict__ kB,
                                                const unsigned short* __restrict__ vB,
                                                const int* __restrict__ mask,
                                                unsigned short* __restrict__ ctxB) {
  const int n = blockIdx.x, h = blockIdx.y, b = blockIdx.z;
  const int c = threadIdx.x;
  const int sq = n * CC + c;
  __shared__ float sK[128 * 64];
  __shared__ float sV[128 * 64];
  __shared__ int sMask[128];
  const size_t headBase = ((size_t)(b * HH + h)) * SS;

  float q[64];
  load64(qB + (headBase + sq) * 64, q);
  float o[64];
#pragma unroll
  for (int d = 0; d < 64; d++) o[d] = 0.f;
  float mx = -1e30f, l = 0.f;

  // global key (position 0)
  if (mask[(size_t)b * SS] != 0) {
    float s = dot64(q, kB + headBase * 64);
    if (s > mx) {
      float so = __expf(mx - s);
      l *= so;
#pragma unroll
      for (int d = 0; d < 64; d++) o[d] *= so;
      mx = s;
    }
    float p = __expf(s - mx);
    l += p;
    axpy64g(p, vB + headBase * 64, o);
  }

  const int kpBase = n * CC - CC;
  for (int ch = 0; ch < 6; ch++) {
    const int kp0 = kpBase + ch * 128;
    __syncthreads();
    // stage K/V chunk (128 keys x 64) as fp32
#pragma unroll
    for (int i = 0; i < 4; i++) {
      const int e = i * 256 + threadIdx.x;   // 0..1023, 8 elems each
      const int row = e >> 3;
      const int d0 = (e & 7) * 8;
      const int kp = kp0 + row;
      int4 t = make_int4(0, 0, 0, 0);
      if (kp >= 0 && kp < SS) t = *reinterpret_cast<const int4*>(kB + (headBase + kp) * 64 + d0);
      float f[8]; unpack8(t, f);
      *reinterpret_cast<float4*>(sK + row * 64 + d0) = make_float4(f[0], f[1], f[2], f[3]);
      *reinterpret_cast<float4*>(sK + row * 64 + d0 + 4) = make_float4(f[4], f[5], f[6], f[7]);
      t = make_int4(0, 0, 0, 0);
      if (kp >= 0 && kp < SS) t = *reinterpret_cast<const int4*>(vB + (headBase + kp) * 64 + d0);
      unpack8(t, f);
      *reinterpret_cast<float4*>(sV + row * 64 + d0) = make_float4(f[0], f[1], f[2], f[3]);
      *reinterpret_cast<float4*>(sV + row * 64 + d0 + 4) = make_float4(f[4], f[5], f[6], f[7]);
    }
    if (threadIdx.x < 128) {
      const int kp = kp0 + threadIdx.x;
      sMask[threadIdx.x] = (kp >= 1 && kp < SS) ? mask[(size_t)b * SS + kp] : 0;
    }
    __syncthreads();

    const int c0 = c & ~63;                 // wave-uniform
    const int kkgBase = ch * 128;
    if (kkgBase + 127 >= c0 && kkgBase <= c0 + 63 + 512 && kp0 + 127 >= 1 && kp0 <= SS - 1) {
      for (int kk = 0; kk < 128; kk++) {
        const int kkg = kkgBase + kk;
        if (kkg < c || kkg > c + 512) continue;     // band
        if (sMask[kk] == 0) continue;
        const float* kv = sK + kk * 64;
        float s = 0.f;
#pragma unroll
        for (int i = 0; i < 16; i++) {
          float4 k4 = *reinterpret_cast<const float4*>(kv + i * 4);
          s = fmaf(q[i * 4 + 0], k4.x, s);
          s = fmaf(q[i * 4 + 1], k4.y, s);
          s = fmaf(q[i * 4 + 2], k4.z, s);
          s = fmaf(q[i * 4 + 3], k4.w, s);
        }
        if (s > mx) {
          float so = __expf(mx - s);
          l *= so;
#pragma unroll
          for (int d = 0; d < 64; d++) o[d] *= so;
          mx = s;
        }
        float p = __expf(s - mx);
        l += p;
        const float* vv = sV + kk * 64;
#pragma unroll
        for (int i = 0; i < 16; i++) {
          float4 v4 = *reinterpret_cast<const float4*>(vv + i * 4);
          o[i * 4 + 0] = fmaf(p, v4.x, o[i * 4 + 0]);
          o[i * 4 + 1] = fmaf(p, v4.y, o[i * 4 + 1]);
          o[i * 4 + 2] = fmaf(p, v4.z, o[i * 4 + 2]);
          o[i * 4 + 3] = fmaf(p, v4.w, o[i * 4 + 3]);
        }
      }
    }
  }
  const float inv = 1.f / l;
  unsigned short* co = ctxB + ((size_t)(b * SS + sq)) * DD + h * 64;
#pragma unroll
  for (int i = 0; i < 8; i++) {
    int4 t;
    t.x = (int)pack2(o[i * 8 + 0] * inv, o[i * 8 + 1] * inv);
    t.y = (int)pack2(o[i * 8 + 2] * inv, o[i * 8 + 3] * inv);
    t.z = (int)pack2(o[i * 8 + 4] * inv, o[i * 8 + 5] * inv);
    t.w = (int)pack2(o[i * 8 + 6] * inv, o[i * 8 + 7] * inv);
    *reinterpret_cast<int4*>(co + i * 8) = t;
  }
}

// ---------- full attention for query position 0 ----------
__global__ __launch_bounds__(256) void attn_row0(const unsigned short* __restrict__ qB,
                                                 const unsigned short* __restrict__ kB,
                                                 const unsigned short* __restrict__ vB,
                                                 const int* __restrict__ mask,
                                                 unsigned short* __restrict__ ctxB) {
  const int h = blockIdx.x, b = blockIdx.y;
  const size_t headBase = ((size_t)(b * HH + h)) * SS;
  float q[64];
  load64(qB + headBase * 64, q);

  float sc[16];
  float lmx = -1e30f;
#pragma unroll
  for (int i = 0; i < 16; i++) {
    const int sidx = i * 256 + threadIdx.x;
    float s = dot64(q, kB + (headBase + sidx) * 64);
    sc[i] = (mask[(size_t)b * SS + sidx] != 0) ? s : -1e9f;
    lmx = fmaxf(lmx, sc[i]);
  }
#pragma unroll
  for (int off = 32; off > 0; off >>= 1) lmx = fmaxf(lmx, __shfl_down(lmx, off));
  __shared__ float rmx[4];
  if ((threadIdx.x & 63) == 0) rmx[threadIdx.x >> 6] = lmx;
  __syncthreads();
  const float Mx = fmaxf(fmaxf(rmx[0], rmx[1]), fmaxf(rmx[2], rmx[3]));

  float lsum = 0.f;
  float o[64];
#pragma unroll
  for (int d = 0; d < 64; d++) o[d] = 0.f;
#pragma unroll
  for (int i = 0; i < 16; i++) {
    const float p = __expf(sc[i] - Mx);
    lsum += p;
    const int sidx = i * 256 + threadIdx.x;
    axpy64g(p, vB + (headBase + sidx) * 64, o);
  }
#pragma unroll
  for (int off = 32; off > 0; off >>= 1) lsum += __shfl_down(lsum, off);
  __shared__ float rls[4];
  if ((threadIdx.x & 63) == 0) rls[threadIdx.x >> 6] = lsum;
  __syncthreads();
  const float L = rls[0] + rls[1] + rls[2] + rls[3];

  __shared__ float sO[256 * 68];
#pragma unroll
  for (int i = 0; i < 16; i++)
    *reinterpret_cast<float4*>(sO + threadIdx.x * 68 + i * 4) =
        make_float4(o[i * 4], o[i * 4 + 1], o[i * 4 + 2], o[i * 4 + 3]);
  __syncthreads();
  if (threadIdx.x < 64) {
    float a = 0.f;
    for (int t = 0; t < 256; t++) a += sO[t * 68 + threadIdx.x];
    ctxB[((size_t)(b * SS)) * DD + h * 64 + threadIdx.x] = f2b(a / L);
  }
}

// ---------- classifier ----------
__global__ __launch_bounds__(256) void cls_head(const float* __restrict__ h32,
                                                const float* __restrict__ W,
                                                const float* __restrict__ bc,
                                                float* __restrict__ out) {
  const int b = blockIdx.x;
  const float* hr = h32 + (size_t)b * SS * DD;
  float p0 = 0.f, p1 = 0.f, p2 = 0.f;
  for (int d = threadIdx.x; d < DD; d += 256) {
    const float x = hr[d];
    p0 = fmaf(x, W[d * 3 + 0], p0);
    p1 = fmaf(x, W[d * 3 + 1], p1);
    p2 = fmaf(x, W[d * 3 + 2], p2);
  }
  __shared__ float r0[256], r1[256], r2[256];
  r0[threadIdx.x] = p0; r1[threadIdx.x] = p1; r2[threadIdx.x] = p2;
  __syncthreads();
  if (threadIdx.x == 0) {
    float s0 = 0.f, s1 = 0.f, s2 = 0.f;
    for (int t = 0; t < 256; t++) { s0 += r0[t]; s1 += r1[t]; s2 += r2[t]; }
    out[b * 3 + 0] = s0 + bc[0];
    out[b * 3 + 1] = s1 + bc[1];
    out[b * 3 + 2] = s2 + bc[2];
  }
}

// ---------- workspace layout (bytes) ----------
static const size_t OFF_WT = 0;             // 14,155,776 bf16 (all transposed weights)
static const size_t OFF_H32 = 28311552;     // MM*DD fp32
static const size_t OFF_HB = 53477376;      // MM*DD bf16
static const size_t OFF_Q = 66060288;       // B*H*S*DH bf16
static const size_t OFF_K = 78643200;
static const size_t OFF_V = 91226112;
static const size_t OFF_CTX = 103809024;    // MM*DD bf16
static const size_t OFF_DELTA = 116391936;  // MM*DD fp32
static const size_t OFF_F1 = 141557760;     // MM*FF bf16
static const size_t WS_NEEDED = 191889408;

extern "C" void kernel_launch(void* const* d_in, const int* in_sizes, int n_in,
                              void* d_out, int out_size, void* d_ws, size_t ws_size,
                              hipStream_t stream) {
  (void)in_sizes; (void)n_in; (void)out_size;
  if (ws_size < WS_NEEDED) return;

  const int* ids = (const int*)d_in[0];
  const int* mask = (const int*)d_in[1];
  const float* emb_tok = (const float*)d_in[2];
  const float* emb_pos = (const float*)d_in[3];
  const float* eg = (const float*)d_in[4];
  const float* eb = (const float*)d_in[5];
  const float* Wq = (const float*)d_in[6];
  const float* bq = (const float*)d_in[7];
  const float* Wk = (const float*)d_in[8];
  const float* bk = (const float*)d_in[9];
  const float* Wv = (const float*)d_in[10];
  const float* bv = (const float*)d_in[11];
  const float* Wo = (const float*)d_in[12];
  const float* bo = (const float*)d_in[13];
  const float* ln1g = (const float*)d_in[14];
  const float* ln1b = (const float*)d_in[15];
  const float* W1 = (const float*)d_in[16];
  const float* b1 = (const float*)d_in[17];
  const float* W2 = (const float*)d_in[18];
  const float* b2 = (const float*)d_in[19];
  const float* ln2g = (const float*)d_in[20];
  const float* ln2b = (const float*)d_in[21];
  const float* clsW = (const float*)d_in[22];
  const float* clsb = (const float*)d_in[23];
  float* out = (float*)d_out;

  char* ws = (char*)d_ws;
  unsigned short* wt = (unsigned short*)(ws + OFF_WT);
  float* h32 = (float*)(ws + OFF_H32);
  unsigned short* hB = (unsigned short*)(ws + OFF_HB);
  unsigned short* qb16 = (unsigned short*)(ws + OFF_Q);
  unsigned short* kb16 = (unsigned short*)(ws + OFF_K);
  unsigned short* vb16 = (unsigned short*)(ws + OFF_V);
  unsigned short* ctxB = (unsigned short*)(ws + OFF_CTX);
  float* delta = (float*)(ws + OFF_DELTA);
  unsigned short* f1B = (unsigned short*)(ws + OFF_F1);

  // transpose all weights to bf16 (N,K)
  for (int l = 0; l < 2; l++) {
    const size_t lw = (size_t)l * 7077888;
    transpose_bf16<<<dim3(24, 24), dim3(32, 8), 0, stream>>>(Wq + (size_t)l * 589824, wt + lw + 0, 768, 768);
    transpose_bf16<<<dim3(24, 24), dim3(32, 8), 0, stream>>>(Wk + (size_t)l * 589824, wt + lw + 589824, 768, 768);
    transpose_bf16<<<dim3(24, 24), dim3(32, 8), 0, stream>>>(Wv + (size_t)l * 589824, wt + lw + 1179648, 768, 768);
    transpose_bf16<<<dim3(24, 24), dim3(32, 8), 0, stream>>>(Wo + (size_t)l * 589824, wt + lw + 1769472, 768, 768);
    transpose_bf16<<<dim3(96, 24), dim3(32, 8), 0, stream>>>(W1 + (size_t)l * 2359296, wt + lw + 2359296, 768, 3072);
    transpose_bf16<<<dim3(24, 96), dim3(32, 8), 0, stream>>>(W2 + (size_t)l * 2359296, wt + lw + 4718592, 3072, 768);
  }

  embed_ln<<<MM, 256, 0, stream>>>(ids, emb_tok, emb_pos, eg, eb, h32, hB);

  for (int l = 0; l < 2; l++) {
    const size_t lw = (size_t)l * 7077888;
    // fused QKV (N = 2304)
    gemm_nt<1><<<dim3(18, 64), 256, 0, stream>>>(hB, wt + lw, bq + l * 768, bk + l * 768,
                                                 bv + l * 768, nullptr, qb16, kb16, vb16,
                                                 MM, 2304, 768);
    attn_win<<<dim3(16, 12, 2), 256, 0, stream>>>(qb16, kb16, vb16, mask, ctxB);
    attn_row0<<<dim3(12, 2), 256, 0, stream>>>(qb16, kb16, vb16, mask, ctxB);
    gemm_nt<0><<<dim3(6, 64), 256, 0, stream>>>(ctxB, wt + lw + 1769472, bo + l * 768, nullptr,
                                                nullptr, delta, nullptr, nullptr, nullptr,
                                                MM, 768, 768);
    ln_res<<<MM, 256, 0, stream>>>(h32, delta, ln1g + l * 768, ln1b + l * 768, hB);
    gemm_nt<2><<<dim3(24, 64), 256, 0, stream>>>(hB, wt + lw + 2359296, b1 + l * 3072, nullptr,
                                                 nullptr, nullptr, f1B, nullptr, nullptr,
                                                 MM, 3072, 768);
    gemm_nt<0><<<dim3(6, 64), 256, 0, stream>>>(f1B, wt + lw + 4718592, b2 + l * 768, nullptr,
                                                nullptr, delta, nullptr, nullptr, nullptr,
                                                MM, 768, 3072);
    ln_res<<<MM, 256, 0, stream>>>(h32, delta, ln2g + l * 768, ln2b + l * 768, hB);
  }

  cls_head<<<dim3(BB), 256, 0, stream>>>(h32, clsW, clsb, out);
}

// Round 2
// 1199.403 us; speedup vs baseline: 1.9132x; 1.9132x over previous
//
#include <hip/hip_runtime.h>
#include <math.h>

#define BB 2
#define SS 4096
#define DD 768
#define HH 12
#define LL 2
#define FF 3072
#define CC 256
#define MM 8192   // B*S
#define QB 128    // queries per attention block

using frag8 = __attribute__((ext_vector_type(8))) short;   // 8 bf16
using f32x4 = __attribute__((ext_vector_type(4))) float;

// ---------- helpers ----------
__device__ __forceinline__ unsigned short f2b(float f) {
  unsigned u = __float_as_uint(f);
  u = u + 0x7fffu + ((u >> 16) & 1u);   // RNE
  return (unsigned short)(u >> 16);
}
__device__ __forceinline__ void unpack8(int4 t, float* f) {
  unsigned u;
  u = (unsigned)t.x; f[0] = __uint_as_float(u << 16); f[1] = __uint_as_float(u & 0xffff0000u);
  u = (unsigned)t.y; f[2] = __uint_as_float(u << 16); f[3] = __uint_as_float(u & 0xffff0000u);
  u = (unsigned)t.z; f[4] = __uint_as_float(u << 16); f[5] = __uint_as_float(u & 0xffff0000u);
  u = (unsigned)t.w; f[6] = __uint_as_float(u << 16); f[7] = __uint_as_float(u & 0xffff0000u);
}
__device__ __forceinline__ void load64(const unsigned short* p, float* q) {
#pragma unroll
  for (int i = 0; i < 8; i++) {
    int4 t = *reinterpret_cast<const int4*>(p + i * 8);
    unpack8(t, q + i * 8);
  }
}
__device__ __forceinline__ float dot64(const float* q, const unsigned short* p) {
  float s = 0.f;
#pragma unroll
  for (int i = 0; i < 8; i++) {
    int4 t = *reinterpret_cast<const int4*>(p + i * 8);
    float f[8]; unpack8(t, f);
#pragma unroll
    for (int j = 0; j < 8; j++) s = fmaf(q[i * 8 + j], f[j], s);
  }
  return s;
}
__device__ __forceinline__ void axpy64g(float pw, const unsigned short* vp, float* o) {
#pragma unroll
  for (int i = 0; i < 8; i++) {
    int4 t = *reinterpret_cast<const int4*>(vp + i * 8);
    float f[8]; unpack8(t, f);
#pragma unroll
    for (int j = 0; j < 8; j++) o[i * 8 + j] = fmaf(pw, f[j], o[i * 8 + j]);
  }
}
__device__ __forceinline__ void reduce2(float& s1, float& s2) {
#pragma unroll
  for (int off = 32; off > 0; off >>= 1) {
    s1 += __shfl_down(s1, off);
    s2 += __shfl_down(s2, off);
  }
  __shared__ float r1[4], r2[4];
  const int lane = threadIdx.x & 63, wv = threadIdx.x >> 6;
  if (lane == 0) { r1[wv] = s1; r2[wv] = s2; }
  __syncthreads();
  s1 = r1[0] + r1[1] + r1[2] + r1[3];
  s2 = r2[0] + r2[1] + r2[2] + r2[3];
  __syncthreads();
}
// async global->LDS, 16B per lane; lds dest = wave-uniform base + lane*16
__device__ __forceinline__ void async16(const unsigned short* g, unsigned short* l) {
  __builtin_amdgcn_global_load_lds((__attribute__((address_space(1))) void*)(g),
                                   (__attribute__((address_space(3))) void*)(l), 16, 0, 0);
}

// ---------- weight transpose fp32(K,N) -> bf16(N,K) ----------
__global__ __launch_bounds__(256) void transpose_bf16(const float* __restrict__ in,
                                                      unsigned short* __restrict__ out,
                                                      int K, int N) {
  __shared__ float t[32][33];
  const int n0 = blockIdx.x * 32, k0 = blockIdx.y * 32;
  const int tx = threadIdx.x, ty = threadIdx.y;   // block (32,8)
#pragma unroll
  for (int i = 0; i < 32; i += 8) t[ty + i][tx] = in[(size_t)(k0 + ty + i) * N + n0 + tx];
  __syncthreads();
#pragma unroll
  for (int i = 0; i < 32; i += 8) out[(size_t)(n0 + ty + i) * K + k0 + tx] = f2b(t[tx][ty + i]);
}

// ---------- embedding + LN ----------
__global__ __launch_bounds__(256) void embed_ln(const int* __restrict__ ids,
                                                const float* __restrict__ etok,
                                                const float* __restrict__ epos,
                                                const float* __restrict__ g,
                                                const float* __restrict__ bb,
                                                float* __restrict__ h32,
                                                unsigned short* __restrict__ hB) {
  const int row = blockIdx.x;
  const int s = row & (SS - 1);
  const int id = ids[row];
  float x[3];
#pragma unroll
  for (int i = 0; i < 3; i++) {
    int j = threadIdx.x + i * 256;
    x[i] = etok[(size_t)id * DD + j] + epos[(size_t)s * DD + j];
  }
  float s1 = x[0] + x[1] + x[2];
  float s2 = x[0] * x[0] + x[1] * x[1] + x[2] * x[2];
  reduce2(s1, s2);
  const float mean = s1 * (1.f / 768.f);
  const float var = s2 * (1.f / 768.f) - mean * mean;
  const float rs = rsqrtf(var + 1e-5f);
#pragma unroll
  for (int i = 0; i < 3; i++) {
    int j = threadIdx.x + i * 256;
    float y = (x[i] - mean) * rs * g[j] + bb[j];
    h32[(size_t)row * DD + j] = y;
    hB[(size_t)row * DD + j] = f2b(y);
  }
}

// ---------- residual + LN ----------
__global__ __launch_bounds__(256) void ln_res(float* __restrict__ h32,
                                              const float* __restrict__ delta,
                                              const float* __restrict__ g,
                                              const float* __restrict__ bb,
                                              unsigned short* __restrict__ hB) {
  const int row = blockIdx.x;
  float x[3];
#pragma unroll
  for (int i = 0; i < 3; i++) {
    int j = threadIdx.x + i * 256;
    x[i] = h32[(size_t)row * DD + j] + delta[(size_t)row * DD + j];
  }
  float s1 = x[0] + x[1] + x[2];
  float s2 = x[0] * x[0] + x[1] * x[1] + x[2] * x[2];
  reduce2(s1, s2);
  const float mean = s1 * (1.f / 768.f);
  const float var = s2 * (1.f / 768.f) - mean * mean;
  const float rs = rsqrtf(var + 1e-5f);
#pragma unroll
  for (int i = 0; i < 3; i++) {
    int j = threadIdx.x + i * 256;
    float y = (x[i] - mean) * rs * g[j] + bb[j];
    h32[(size_t)row * DD + j] = y;
    hB[(size_t)row * DD + j] = f2b(y);
  }
}

// ---------- bf16 MFMA GEMM:  C(M,N) = A(M,K) @ Bt(N,K)^T + bias ----------
// global_load_lds (width 16) staging, m97 structure.
// EPI 0: fp32 row-major (outF, bias0)
// EPI 1: fused QKV scatter -> (B,H,S,DH) bf16, q scaled 0.125 (N=2304)
// EPI 2: GELU -> bf16 row-major (oq, bias0)
template <int EPI>
__global__ __launch_bounds__(256) void gemm_nt(const unsigned short* __restrict__ A,
                                               const unsigned short* __restrict__ Bt,
                                               const float* __restrict__ bias0,
                                               const float* __restrict__ bias1,
                                               const float* __restrict__ bias2,
                                               float* __restrict__ outF,
                                               unsigned short* __restrict__ oq,
                                               unsigned short* __restrict__ ok,
                                               unsigned short* __restrict__ ov,
                                               int M, int N, int K) {
  __shared__ unsigned short sA[128 * 32];
  __shared__ unsigned short sB[128 * 32];
  const int tid = threadIdx.x;
  const int m0 = blockIdx.y * 128, n0 = blockIdx.x * 128;
  const int wave = tid >> 6, lane = tid & 63;
  const int wm = (wave >> 1) * 64, wn = (wave & 1) * 64;
  const int quad = lane >> 4, r16 = lane & 15;

  // staging: wave w covers rows [w*32, w*32+32) in two 16-row issues
  const int srow = wave * 32 + (lane >> 2);
  const int scol = (lane & 3) * 8;
  const unsigned short* gA0 = A + (size_t)(m0 + srow) * K + scol;
  const unsigned short* gA1 = gA0 + (size_t)16 * K;
  const unsigned short* gB0 = Bt + (size_t)(n0 + srow) * K + scol;
  const unsigned short* gB1 = gB0 + (size_t)16 * K;
  unsigned short* lA0 = &sA[(wave * 32) * 32];
  unsigned short* lA1 = &sA[(wave * 32 + 16) * 32];
  unsigned short* lB0 = &sB[(wave * 32) * 32];
  unsigned short* lB1 = &sB[(wave * 32 + 16) * 32];

  f32x4 acc[4][4];
#pragma unroll
  for (int i = 0; i < 4; i++)
#pragma unroll
    for (int j = 0; j < 4; j++) acc[i][j] = (f32x4){0.f, 0.f, 0.f, 0.f};

  const int kiters = K >> 5;
  for (int kt = 0; kt < kiters; kt++) {
    const int k0 = kt << 5;
    __syncthreads();
    async16(gA0 + k0, lA0);
    async16(gA1 + k0, lA1);
    async16(gB0 + k0, lB0);
    async16(gB1 + k0, lB1);
    __syncthreads();   // drains vmcnt(0)
    frag8 af[4], bf[4];
#pragma unroll
    for (int i = 0; i < 4; i++)
      af[i] = *reinterpret_cast<const frag8*>(&sA[(wm + i * 16 + r16) * 32 + quad * 8]);
#pragma unroll
    for (int j = 0; j < 4; j++)
      bf[j] = *reinterpret_cast<const frag8*>(&sB[(wn + j * 16 + r16) * 32 + quad * 8]);
#pragma unroll
    for (int i = 0; i < 4; i++)
#pragma unroll
      for (int j = 0; j < 4; j++)
        acc[i][j] = __builtin_amdgcn_mfma_f32_16x16x32_bf16(af[i], bf[j], acc[i][j], 0, 0, 0);
  }

#pragma unroll
  for (int i = 0; i < 4; i++)
#pragma unroll
    for (int j = 0; j < 4; j++)
#pragma unroll
      for (int rr = 0; rr < 4; rr++) {
        const int row = m0 + wm + i * 16 + quad * 4 + rr;
        const int col = n0 + wn + j * 16 + r16;
        if (EPI == 0) {
          outF[(size_t)row * N + col] = acc[i][j][rr] + bias0[col];
        } else if (EPI == 1) {
          const int which = col / 768;
          const int hd = col - which * 768;
          const float bsv = (which == 0) ? bias0[hd] : (which == 1) ? bias1[hd] : bias2[hd];
          float v = acc[i][j][rr] + bsv;
          if (which == 0) v *= 0.125f;
          unsigned short* dst = (which == 0) ? oq : (which == 1) ? ok : ov;
          const int bq = row >> 12, sq = row & (SS - 1);
          dst[((size_t)(bq * HH + (hd >> 6)) * SS + sq) * 64 + (hd & 63)] = f2b(v);
        } else {
          float v = acc[i][j][rr] + bias0[col];
          float ge = 0.5f * v * (1.f + erff(v * 0.70710678118654752f));
          oq[(size_t)row * N + col] = f2b(ge);
        }
      }
}

// ---------- MFMA flash sliding-window attention ----------
// block = 256 thr (4 waves), handles QB=128 queries of (b,h); wave owns 32.
// 11 chunks: chunk -1 = global key 0 (masked to col 0), then 10 x 64-key window.
__global__ __launch_bounds__(256) void attn_win(const unsigned short* __restrict__ qB,
                                                const unsigned short* __restrict__ kB,
                                                const unsigned short* __restrict__ vB,
                                                const int* __restrict__ mask,
                                                unsigned short* __restrict__ ctxB) {
  const int n = blockIdx.x, h = blockIdx.y, b = blockIdx.z;
  const int tid = threadIdx.x;
  const int wave = tid >> 6, lane = tid & 63;
  const int quad = lane >> 4, r16 = lane & 15;
  const size_t headBase = ((size_t)(b * HH + h)) * SS;

  __shared__ unsigned short sK[64 * 72];        // keys x d, stride 72
  __shared__ unsigned short sVt[64 * 72];       // d x keys, stride 72
  __shared__ unsigned short sP[4][32 * 72];     // per-wave P, stride 72
  __shared__ int sM[64];

  const int qw0 = n * QB + wave * 32;

  // Q fragments (A-layout): qf[mt][kh], lane holds Q[qw0+mt*16+r16][kh*32+quad*8+j]
  frag8 qf[2][2];
#pragma unroll
  for (int mt = 0; mt < 2; mt++)
#pragma unroll
    for (int kh = 0; kh < 2; kh++) {
      int4 t = *reinterpret_cast<const int4*>(
          qB + (headBase + qw0 + mt * 16 + r16) * 64 + kh * 32 + quad * 8);
      qf[mt][kh] = *reinterpret_cast<frag8*>(&t);
    }

  f32x4 oacc[2][4];
#pragma unroll
  for (int mt = 0; mt < 2; mt++)
#pragma unroll
    for (int dt = 0; dt < 4; dt++) oacc[mt][dt] = (f32x4){0.f, 0.f, 0.f, 0.f};
  float mx[2][4], li[2][4];
#pragma unroll
  for (int mt = 0; mt < 2; mt++)
#pragma unroll
    for (int rr = 0; rr < 4; rr++) { mx[mt][rr] = -1e30f; li[mt][rr] = 0.f; }

  const int kbase = n * QB - 256;
  for (int ch = -1; ch < 10; ch++) {
    const int kc = kbase + ch * 64;
    const bool isG = (ch < 0);
    __syncthreads();
    // ---- stage K (row-major) ----
    {
      const int key = tid >> 2, d0 = (tid & 3) * 16;
      const int kp = isG ? ((key == 0) ? 0 : -1) : kc + key;
      int4 a = make_int4(0, 0, 0, 0), c = make_int4(0, 0, 0, 0);
      if (kp >= 0 && kp < SS) {
        const unsigned short* src = kB + (headBase + kp) * 64 + d0;
        a = *reinterpret_cast<const int4*>(src);
        c = *reinterpret_cast<const int4*>(src + 8);
      }
      *reinterpret_cast<int4*>(&sK[key * 72 + d0]) = a;
      *reinterpret_cast<int4*>(&sK[key * 72 + d0 + 8]) = c;
    }
    // ---- stage V transposed ----
    {
      const int key = tid & 63, d0 = (tid >> 6) * 16;
      const int kp = isG ? ((key == 0) ? 0 : -1) : kc + key;
      int4 a = make_int4(0, 0, 0, 0), c = make_int4(0, 0, 0, 0);
      if (kp >= 0 && kp < SS) {
        const unsigned short* src = vB + (headBase + kp) * 64 + d0;
        a = *reinterpret_cast<const int4*>(src);
        c = *reinterpret_cast<const int4*>(src + 8);
      }
      unsigned short e[16];
      *reinterpret_cast<int4*>(&e[0]) = a;
      *reinterpret_cast<int4*>(&e[8]) = c;
#pragma unroll
      for (int j = 0; j < 16; j++) sVt[(d0 + j) * 72 + key] = e[j];
    }
    if (tid < 64) {
      int ok;
      if (isG) ok = (tid == 0) ? mask[(size_t)b * SS] : 0;
      else {
        const int kp = kc + tid;
        ok = (kp >= 1 && kp < SS) ? mask[(size_t)b * SS + kp] : 0;
      }
      sM[tid] = ok;
    }
    __syncthreads();

    // wave band skip (compute only; barriers stay uniform)
    if (!isG && (kc > qw0 + 31 + 256 || kc + 63 < qw0 - 256)) continue;

    // ---- QK^T ----
    f32x4 sacc[2][4];
#pragma unroll
    for (int mt = 0; mt < 2; mt++)
#pragma unroll
      for (int nt = 0; nt < 4; nt++) sacc[mt][nt] = (f32x4){0.f, 0.f, 0.f, 0.f};
#pragma unroll
    for (int kh = 0; kh < 2; kh++) {
      frag8 kf[4];
#pragma unroll
      for (int nt = 0; nt < 4; nt++)
        kf[nt] = *reinterpret_cast<const frag8*>(&sK[(nt * 16 + r16) * 72 + kh * 32 + quad * 8]);
#pragma unroll
      for (int mt = 0; mt < 2; mt++)
#pragma unroll
        for (int nt = 0; nt < 4; nt++)
          sacc[mt][nt] = __builtin_amdgcn_mfma_f32_16x16x32_bf16(qf[mt][kh], kf[nt], sacc[mt][nt], 0, 0, 0);
    }

    // ---- masking + online softmax ----
    int mreg[4];
#pragma unroll
    for (int nt = 0; nt < 4; nt++) mreg[nt] = sM[nt * 16 + r16];
    float al[2][4];
#pragma unroll
    for (int mt = 0; mt < 2; mt++) {
      float rmax[4] = {-1e30f, -1e30f, -1e30f, -1e30f};
#pragma unroll
      for (int nt = 0; nt < 4; nt++) {
        const int kp = isG ? 0 : kc + nt * 16 + r16;
#pragma unroll
        for (int rr = 0; rr < 4; rr++) {
          const int sq = qw0 + mt * 16 + quad * 4 + rr;
          const bool valid = (mreg[nt] != 0) && (isG || (unsigned)(kp - sq + 256) <= 512u);
          const float sv = valid ? sacc[mt][nt][rr] : -1e30f;
          sacc[mt][nt][rr] = sv;
          rmax[rr] = fmaxf(rmax[rr], sv);
        }
      }
#pragma unroll
      for (int rr = 0; rr < 4; rr++) {
#pragma unroll
        for (int off = 1; off < 16; off <<= 1)
          rmax[rr] = fmaxf(rmax[rr], __shfl_xor(rmax[rr], off, 64));
        const float mnew = fmaxf(mx[mt][rr], rmax[rr]);
        al[mt][rr] = __expf(mx[mt][rr] - mnew);
        mx[mt][rr] = mnew;
      }
      float rsum[4] = {0.f, 0.f, 0.f, 0.f};
#pragma unroll
      for (int nt = 0; nt < 4; nt++)
#pragma unroll
        for (int rr = 0; rr < 4; rr++) {
          const float sv = sacc[mt][nt][rr];
          const float p = (sv < -5e29f) ? 0.f : __expf(sv - mx[mt][rr]);
          rsum[rr] += p;
          sP[wave][(mt * 16 + quad * 4 + rr) * 72 + nt * 16 + r16] = f2b(p);
        }
#pragma unroll
      for (int rr = 0; rr < 4; rr++) {
#pragma unroll
        for (int off = 1; off < 16; off <<= 1) rsum[rr] += __shfl_xor(rsum[rr], off, 64);
        li[mt][rr] = li[mt][rr] * al[mt][rr] + rsum[rr];
      }
#pragma unroll
      for (int dt = 0; dt < 4; dt++)
#pragma unroll
        for (int rr = 0; rr < 4; rr++) oacc[mt][dt][rr] *= al[mt][rr];
    }

    // ---- PV (P from per-wave LDS, same-wave DS ops are in-order) ----
#pragma unroll
    for (int kh = 0; kh < 2; kh++) {
      frag8 pf[2], vf[4];
#pragma unroll
      for (int mt = 0; mt < 2; mt++)
        pf[mt] = *reinterpret_cast<const frag8*>(&sP[wave][(mt * 16 + r16) * 72 + kh * 32 + quad * 8]);
#pragma unroll
      for (int dt = 0; dt < 4; dt++)
        vf[dt] = *reinterpret_cast<const frag8*>(&sVt[(dt * 16 + r16) * 72 + kh * 32 + quad * 8]);
#pragma unroll
      for (int mt = 0; mt < 2; mt++)
#pragma unroll
        for (int dt = 0; dt < 4; dt++)
          oacc[mt][dt] = __builtin_amdgcn_mfma_f32_16x16x32_bf16(pf[mt], vf[dt], oacc[mt][dt], 0, 0, 0);
    }
  }

  // ---- epilogue ----
#pragma unroll
  for (int mt = 0; mt < 2; mt++) {
    float rli[4];
#pragma unroll
    for (int rr = 0; rr < 4; rr++) rli[rr] = 1.f / li[mt][rr];
#pragma unroll
    for (int dt = 0; dt < 4; dt++)
#pragma unroll
      for (int rr = 0; rr < 4; rr++) {
        const int sq = qw0 + mt * 16 + quad * 4 + rr;
        const int d = dt * 16 + r16;
        ctxB[((size_t)(b * SS + sq)) * DD + h * 64 + d] = f2b(oacc[mt][dt][rr] * rli[rr]);
      }
  }
}

// ---------- full attention for query position 0 ----------
__global__ __launch_bounds__(256) void attn_row0(const unsigned short* __restrict__ qB,
                                                 const unsigned short* __restrict__ kB,
                                                 const unsigned short* __restrict__ vB,
                                                 const int* __restrict__ mask,
                                                 unsigned short* __restrict__ ctxB) {
  const int h = blockIdx.x, b = blockIdx.y;
  const size_t headBase = ((size_t)(b * HH + h)) * SS;
  float q[64];
  load64(qB + headBase * 64, q);

  float sc[16];
  float lmx = -1e30f;
#pragma unroll
  for (int i = 0; i < 16; i++) {
    const int sidx = i * 256 + threadIdx.x;
    float s = dot64(q, kB + (headBase + sidx) * 64);
    sc[i] = (mask[(size_t)b * SS + sidx] != 0) ? s : -1e9f;
    lmx = fmaxf(lmx, sc[i]);
  }
#pragma unroll
  for (int off = 32; off > 0; off >>= 1) lmx = fmaxf(lmx, __shfl_down(lmx, off));
  __shared__ float rmx[4];
  if ((threadIdx.x & 63) == 0) rmx[threadIdx.x >> 6] = lmx;
  __syncthreads();
  const float Mx = fmaxf(fmaxf(rmx[0], rmx[1]), fmaxf(rmx[2], rmx[3]));

  float lsum = 0.f;
  float o[64];
#pragma unroll
  for (int d = 0; d < 64; d++) o[d] = 0.f;
#pragma unroll
  for (int i = 0; i < 16; i++) {
    const float p = __expf(sc[i] - Mx);
    lsum += p;
    const int sidx = i * 256 + threadIdx.x;
    axpy64g(p, vB + (headBase + sidx) * 64, o);
  }
#pragma unroll
  for (int off = 32; off > 0; off >>= 1) lsum += __shfl_down(lsum, off);
  __shared__ float rls[4];
  if ((threadIdx.x & 63) == 0) rls[threadIdx.x >> 6] = lsum;
  __syncthreads();
  const float L = rls[0] + rls[1] + rls[2] + rls[3];

  __shared__ float sO[256 * 68];
#pragma unroll
  for (int i = 0; i < 16; i++)
    *reinterpret_cast<float4*>(sO + threadIdx.x * 68 + i * 4) =
        make_float4(o[i * 4], o[i * 4 + 1], o[i * 4 + 2], o[i * 4 + 3]);
  __syncthreads();
  if (threadIdx.x < 64) {
    float a = 0.f;
    for (int t = 0; t < 256; t++) a += sO[t * 68 + threadIdx.x];
    ctxB[((size_t)(b * SS)) * DD + h * 64 + threadIdx.x] = f2b(a / L);
  }
}

// ---------- classifier ----------
__global__ __launch_bounds__(256) void cls_head(const float* __restrict__ h32,
                                                const float* __restrict__ W,
                                                const float* __restrict__ bc,
                                                float* __restrict__ out) {
  const int b = blockIdx.x;
  const float* hr = h32 + (size_t)b * SS * DD;
  float p0 = 0.f, p1 = 0.f, p2 = 0.f;
  for (int d = threadIdx.x; d < DD; d += 256) {
    const float x = hr[d];
    p0 = fmaf(x, W[d * 3 + 0], p0);
    p1 = fmaf(x, W[d * 3 + 1], p1);
    p2 = fmaf(x, W[d * 3 + 2], p2);
  }
  __shared__ float r0[256], r1[256], r2[256];
  r0[threadIdx.x] = p0; r1[threadIdx.x] = p1; r2[threadIdx.x] = p2;
  __syncthreads();
  if (threadIdx.x == 0) {
    float s0 = 0.f, s1 = 0.f, s2 = 0.f;
    for (int t = 0; t < 256; t++) { s0 += r0[t]; s1 += r1[t]; s2 += r2[t]; }
    out[b * 3 + 0] = s0 + bc[0];
    out[b * 3 + 1] = s1 + bc[1];
    out[b * 3 + 2] = s2 + bc[2];
  }
}

// ---------- workspace layout (bytes) ----------
static const size_t OFF_WT = 0;             // transposed weights, bf16
static const size_t OFF_H32 = 28311552;     // MM*DD fp32
static const size_t OFF_HB = 53477376;      // MM*DD bf16
static const size_t OFF_Q = 66060288;       // B*H*S*DH bf16
static const size_t OFF_K = 78643200;
static const size_t OFF_V = 91226112;
static const size_t OFF_CTX = 103809024;    // MM*DD bf16
static const size_t OFF_DELTA = 116391936;  // MM*DD fp32
static const size_t OFF_F1 = 141557760;     // MM*FF bf16
static const size_t WS_NEEDED = 191889408;

extern "C" void kernel_launch(void* const* d_in, const int* in_sizes, int n_in,
                              void* d_out, int out_size, void* d_ws, size_t ws_size,
                              hipStream_t stream) {
  (void)in_sizes; (void)n_in; (void)out_size;
  if (ws_size < WS_NEEDED) return;

  const int* ids = (const int*)d_in[0];
  const int* mask = (const int*)d_in[1];
  const float* emb_tok = (const float*)d_in[2];
  const float* emb_pos = (const float*)d_in[3];
  const float* eg = (const float*)d_in[4];
  const float* eb = (const float*)d_in[5];
  const float* Wq = (const float*)d_in[6];
  const float* bq = (const float*)d_in[7];
  const float* Wk = (const float*)d_in[8];
  const float* bk = (const float*)d_in[9];
  const float* Wv = (const float*)d_in[10];
  const float* bv = (const float*)d_in[11];
  const float* Wo = (const float*)d_in[12];
  const float* bo = (const float*)d_in[13];
  const float* ln1g = (const float*)d_in[14];
  const float* ln1b = (const float*)d_in[15];
  const float* W1 = (const float*)d_in[16];
  const float* b1 = (const float*)d_in[17];
  const float* W2 = (const float*)d_in[18];
  const float* b2 = (const float*)d_in[19];
  const float* ln2g = (const float*)d_in[20];
  const float* ln2b = (const float*)d_in[21];
  const float* clsW = (const float*)d_in[22];
  const float* clsb = (const float*)d_in[23];
  float* out = (float*)d_out;

  char* ws = (char*)d_ws;
  unsigned short* wt = (unsigned short*)(ws + OFF_WT);
  float* h32 = (float*)(ws + OFF_H32);
  unsigned short* hB = (unsigned short*)(ws + OFF_HB);
  unsigned short* qb16 = (unsigned short*)(ws + OFF_Q);
  unsigned short* kb16 = (unsigned short*)(ws + OFF_K);
  unsigned short* vb16 = (unsigned short*)(ws + OFF_V);
  unsigned short* ctxB = (unsigned short*)(ws + OFF_CTX);
  float* delta = (float*)(ws + OFF_DELTA);
  unsigned short* f1B = (unsigned short*)(ws + OFF_F1);

  for (int l = 0; l < 2; l++) {
    const size_t lw = (size_t)l * 7077888;
    transpose_bf16<<<dim3(24, 24), dim3(32, 8), 0, stream>>>(Wq + (size_t)l * 589824, wt + lw + 0, 768, 768);
    transpose_bf16<<<dim3(24, 24), dim3(32, 8), 0, stream>>>(Wk + (size_t)l * 589824, wt + lw + 589824, 768, 768);
    transpose_bf16<<<dim3(24, 24), dim3(32, 8), 0, stream>>>(Wv + (size_t)l * 589824, wt + lw + 1179648, 768, 768);
    transpose_bf16<<<dim3(24, 24), dim3(32, 8), 0, stream>>>(Wo + (size_t)l * 589824, wt + lw + 1769472, 768, 768);
    transpose_bf16<<<dim3(96, 24), dim3(32, 8), 0, stream>>>(W1 + (size_t)l * 2359296, wt + lw + 2359296, 768, 3072);
    transpose_bf16<<<dim3(24, 96), dim3(32, 8), 0, stream>>>(W2 + (size_t)l * 2359296, wt + lw + 4718592, 3072, 768);
  }

  embed_ln<<<MM, 256, 0, stream>>>(ids, emb_tok, emb_pos, eg, eb, h32, hB);

  for (int l = 0; l < 2; l++) {
    const size_t lw = (size_t)l * 7077888;
    gemm_nt<1><<<dim3(18, 64), 256, 0, stream>>>(hB, wt + lw, bq + l * 768, bk + l * 768,
                                                 bv + l * 768, nullptr, qb16, kb16, vb16,
                                                 MM, 2304, 768);
    attn_win<<<dim3(SS / QB, 12, 2), 256, 0, stream>>>(qb16, kb16, vb16, mask, ctxB);
    attn_row0<<<dim3(12, 2), 256, 0, stream>>>(qb16, kb16, vb16, mask, ctxB);
    gemm_nt<0><<<dim3(6, 64), 256, 0, stream>>>(ctxB, wt + lw + 1769472, bo + l * 768, nullptr,
                                                nullptr, delta, nullptr, nullptr, nullptr,
                                                MM, 768, 768);
    ln_res<<<MM, 256, 0, stream>>>(h32, delta, ln1g + l * 768, ln1b + l * 768, hB);
    gemm_nt<2><<<dim3(24, 64), 256, 0, stream>>>(hB, wt + lw + 2359296, b1 + l * 3072, nullptr,
                                                 nullptr, nullptr, f1B, nullptr, nullptr,
                                                 MM, 3072, 768);
    gemm_nt<0><<<dim3(6, 64), 256, 0, stream>>>(f1B, wt + lw + 4718592, b2 + l * 768, nullptr,
                                                nullptr, delta, nullptr, nullptr, nullptr,
                                                MM, 768, 3072);
    ln_res<<<MM, 256, 0, stream>>>(h32, delta, ln2g + l * 768, ln2b + l * 768, hB);
  }

  cls_head<<<dim3(BB), 256, 0, stream>>>(h32, clsW, clsb, out);
}

// Round 3
// 1030.034 us; speedup vs baseline: 2.2278x; 1.1644x over previous
//
#include <hip/hip_runtime.h>
#include <math.h>

#define BB 2
#define SS 4096
#define DD 768
#define HH 12
#define LL 2
#define FF 3072
#define CC 256
#define MM 8192   // B*S
#define QB 128    // queries per attention block

using frag8 = __attribute__((ext_vector_type(8))) short;   // 8 bf16
using f32x4 = __attribute__((ext_vector_type(4))) float;

// ---------- helpers ----------
__device__ __forceinline__ unsigned short f2b(float f) {
  unsigned u = __float_as_uint(f);
  u = u + 0x7fffu + ((u >> 16) & 1u);   // RNE
  return (unsigned short)(u >> 16);
}
__device__ __forceinline__ void unpack8(int4 t, float* f) {
  unsigned u;
  u = (unsigned)t.x; f[0] = __uint_as_float(u << 16); f[1] = __uint_as_float(u & 0xffff0000u);
  u = (unsigned)t.y; f[2] = __uint_as_float(u << 16); f[3] = __uint_as_float(u & 0xffff0000u);
  u = (unsigned)t.z; f[4] = __uint_as_float(u << 16); f[5] = __uint_as_float(u & 0xffff0000u);
  u = (unsigned)t.w; f[6] = __uint_as_float(u << 16); f[7] = __uint_as_float(u & 0xffff0000u);
}
__device__ __forceinline__ void reduce2(float& s1, float& s2) {
#pragma unroll
  for (int off = 32; off > 0; off >>= 1) {
    s1 += __shfl_down(s1, off);
    s2 += __shfl_down(s2, off);
  }
  __shared__ float r1[4], r2[4];
  const int lane = threadIdx.x & 63, wv = threadIdx.x >> 6;
  if (lane == 0) { r1[wv] = s1; r2[wv] = s2; }
  __syncthreads();
  s1 = r1[0] + r1[1] + r1[2] + r1[3];
  s2 = r2[0] + r2[1] + r2[2] + r2[3];
  __syncthreads();
}
// async global->LDS, 16B per lane; lds dest = wave-uniform base + lane*16
__device__ __forceinline__ void async16(const unsigned short* g, unsigned short* l) {
  __builtin_amdgcn_global_load_lds((__attribute__((address_space(1))) void*)(g),
                                   (__attribute__((address_space(3))) void*)(l), 16, 0, 0);
}

// ---------- weight transpose fp32(K,N) -> bf16(N,K) ----------
__global__ __launch_bounds__(256) void transpose_bf16(const float* __restrict__ in,
                                                      unsigned short* __restrict__ out,
                                                      int K, int N) {
  __shared__ float t[32][33];
  const int n0 = blockIdx.x * 32, k0 = blockIdx.y * 32;
  const int tx = threadIdx.x, ty = threadIdx.y;   // block (32,8)
#pragma unroll
  for (int i = 0; i < 32; i += 8) t[ty + i][tx] = in[(size_t)(k0 + ty + i) * N + n0 + tx];
  __syncthreads();
#pragma unroll
  for (int i = 0; i < 32; i += 8) out[(size_t)(n0 + ty + i) * K + k0 + tx] = f2b(t[tx][ty + i]);
}

// ---------- embedding + LN ----------
__global__ __launch_bounds__(256) void embed_ln(const int* __restrict__ ids,
                                                const float* __restrict__ etok,
                                                const float* __restrict__ epos,
                                                const float* __restrict__ g,
                                                const float* __restrict__ bb,
                                                float* __restrict__ h32,
                                                unsigned short* __restrict__ hB) {
  const int row = blockIdx.x;
  const int s = row & (SS - 1);
  const int id = ids[row];
  float x[3];
#pragma unroll
  for (int i = 0; i < 3; i++) {
    int j = threadIdx.x + i * 256;
    x[i] = etok[(size_t)id * DD + j] + epos[(size_t)s * DD + j];
  }
  float s1 = x[0] + x[1] + x[2];
  float s2 = x[0] * x[0] + x[1] * x[1] + x[2] * x[2];
  reduce2(s1, s2);
  const float mean = s1 * (1.f / 768.f);
  const float var = s2 * (1.f / 768.f) - mean * mean;
  const float rs = rsqrtf(var + 1e-5f);
#pragma unroll
  for (int i = 0; i < 3; i++) {
    int j = threadIdx.x + i * 256;
    float y = (x[i] - mean) * rs * g[j] + bb[j];
    h32[(size_t)row * DD + j] = y;
    hB[(size_t)row * DD + j] = f2b(y);
  }
}

// ---------- residual + LN ----------
__global__ __launch_bounds__(256) void ln_res(float* __restrict__ h32,
                                              const float* __restrict__ delta,
                                              const float* __restrict__ g,
                                              const float* __restrict__ bb,
                                              unsigned short* __restrict__ hB) {
  const int row = blockIdx.x;
  float x[3];
#pragma unroll
  for (int i = 0; i < 3; i++) {
    int j = threadIdx.x + i * 256;
    x[i] = h32[(size_t)row * DD + j] + delta[(size_t)row * DD + j];
  }
  float s1 = x[0] + x[1] + x[2];
  float s2 = x[0] * x[0] + x[1] * x[1] + x[2] * x[2];
  reduce2(s1, s2);
  const float mean = s1 * (1.f / 768.f);
  const float var = s2 * (1.f / 768.f) - mean * mean;
  const float rs = rsqrtf(var + 1e-5f);
#pragma unroll
  for (int i = 0; i < 3; i++) {
    int j = threadIdx.x + i * 256;
    float y = (x[i] - mean) * rs * g[j] + bb[j];
    h32[(size_t)row * DD + j] = y;
    hB[(size_t)row * DD + j] = f2b(y);
  }
}

// ---------- bf16 MFMA GEMM:  C(M,N) = A(M,K) @ Bt(N,K)^T + bias ----------
// global_load_lds (width 16) staging, m97 structure.
// EPI 0: fp32 row-major (outF, bias0)
// EPI 1: fused QKV scatter -> (B,H,S,DH) bf16, q scaled 0.125 (N=2304)
// EPI 2: GELU -> bf16 row-major (oq, bias0)
template <int EPI>
__global__ __launch_bounds__(256) void gemm_nt(const unsigned short* __restrict__ A,
                                               const unsigned short* __restrict__ Bt,
                                               const float* __restrict__ bias0,
                                               const float* __restrict__ bias1,
                                               const float* __restrict__ bias2,
                                               float* __restrict__ outF,
                                               unsigned short* __restrict__ oq,
                                               unsigned short* __restrict__ ok,
                                               unsigned short* __restrict__ ov,
                                               int M, int N, int K) {
  __shared__ unsigned short sA[128 * 32];
  __shared__ unsigned short sB[128 * 32];
  const int tid = threadIdx.x;
  const int m0 = blockIdx.y * 128, n0 = blockIdx.x * 128;
  const int wave = tid >> 6, lane = tid & 63;
  const int wm = (wave >> 1) * 64, wn = (wave & 1) * 64;
  const int quad = lane >> 4, r16 = lane & 15;

  // staging: wave w covers rows [w*32, w*32+32) in two 16-row issues
  const int srow = wave * 32 + (lane >> 2);
  const int scol = (lane & 3) * 8;
  const unsigned short* gA0 = A + (size_t)(m0 + srow) * K + scol;
  const unsigned short* gA1 = gA0 + (size_t)16 * K;
  const unsigned short* gB0 = Bt + (size_t)(n0 + srow) * K + scol;
  const unsigned short* gB1 = gB0 + (size_t)16 * K;
  unsigned short* lA0 = &sA[(wave * 32) * 32];
  unsigned short* lA1 = &sA[(wave * 32 + 16) * 32];
  unsigned short* lB0 = &sB[(wave * 32) * 32];
  unsigned short* lB1 = &sB[(wave * 32 + 16) * 32];

  f32x4 acc[4][4];
#pragma unroll
  for (int i = 0; i < 4; i++)
#pragma unroll
    for (int j = 0; j < 4; j++) acc[i][j] = (f32x4){0.f, 0.f, 0.f, 0.f};

  const int kiters = K >> 5;
  for (int kt = 0; kt < kiters; kt++) {
    const int k0 = kt << 5;
    __syncthreads();
    async16(gA0 + k0, lA0);
    async16(gA1 + k0, lA1);
    async16(gB0 + k0, lB0);
    async16(gB1 + k0, lB1);
    __syncthreads();   // drains vmcnt(0)
    frag8 af[4], bf[4];
#pragma unroll
    for (int i = 0; i < 4; i++)
      af[i] = *reinterpret_cast<const frag8*>(&sA[(wm + i * 16 + r16) * 32 + quad * 8]);
#pragma unroll
    for (int j = 0; j < 4; j++)
      bf[j] = *reinterpret_cast<const frag8*>(&sB[(wn + j * 16 + r16) * 32 + quad * 8]);
#pragma unroll
    for (int i = 0; i < 4; i++)
#pragma unroll
      for (int j = 0; j < 4; j++)
        acc[i][j] = __builtin_amdgcn_mfma_f32_16x16x32_bf16(af[i], bf[j], acc[i][j], 0, 0, 0);
  }

#pragma unroll
  for (int i = 0; i < 4; i++)
#pragma unroll
    for (int j = 0; j < 4; j++)
#pragma unroll
      for (int rr = 0; rr < 4; rr++) {
        const int row = m0 + wm + i * 16 + quad * 4 + rr;
        const int col = n0 + wn + j * 16 + r16;
        if (EPI == 0) {
          outF[(size_t)row * N + col] = acc[i][j][rr] + bias0[col];
        } else if (EPI == 1) {
          const int which = col / 768;
          const int hd = col - which * 768;
          const float bsv = (which == 0) ? bias0[hd] : (which == 1) ? bias1[hd] : bias2[hd];
          float v = acc[i][j][rr] + bsv;
          if (which == 0) v *= 0.125f;
          unsigned short* dst = (which == 0) ? oq : (which == 1) ? ok : ov;
          const int bq = row >> 12, sq = row & (SS - 1);
          dst[((size_t)(bq * HH + (hd >> 6)) * SS + sq) * 64 + (hd & 63)] = f2b(v);
        } else {
          float v = acc[i][j][rr] + bias0[col];
          float ge = 0.5f * v * (1.f + erff(v * 0.70710678118654752f));
          oq[(size_t)row * N + col] = f2b(ge);
        }
      }
}

// ---------- MFMA flash sliding-window attention ----------
// block = 256 thr (4 waves), handles QB=128 queries of (b,h); wave owns 32.
// 11 chunks: chunk -1 = global key 0 (masked to col 0), then 10 x 64-key window.
__global__ __launch_bounds__(256) void attn_win(const unsigned short* __restrict__ qB,
                                                const unsigned short* __restrict__ kB,
                                                const unsigned short* __restrict__ vB,
                                                const int* __restrict__ mask,
                                                unsigned short* __restrict__ ctxB) {
  const int n = blockIdx.x, h = blockIdx.y, b = blockIdx.z;
  const int tid = threadIdx.x;
  const int wave = tid >> 6, lane = tid & 63;
  const int quad = lane >> 4, r16 = lane & 15;
  const size_t headBase = ((size_t)(b * HH + h)) * SS;

  __shared__ unsigned short sK[64 * 72];        // keys x d, stride 72
  __shared__ unsigned short sVt[64 * 72];       // d x keys, stride 72
  __shared__ unsigned short sP[4][32 * 72];     // per-wave P, stride 72
  __shared__ int sM[64];

  const int qw0 = n * QB + wave * 32;

  // Q fragments (A-layout): qf[mt][kh], lane holds Q[qw0+mt*16+r16][kh*32+quad*8+j]
  frag8 qf[2][2];
#pragma unroll
  for (int mt = 0; mt < 2; mt++)
#pragma unroll
    for (int kh = 0; kh < 2; kh++) {
      int4 t = *reinterpret_cast<const int4*>(
          qB + (headBase + qw0 + mt * 16 + r16) * 64 + kh * 32 + quad * 8);
      qf[mt][kh] = *reinterpret_cast<frag8*>(&t);
    }

  f32x4 oacc[2][4];
#pragma unroll
  for (int mt = 0; mt < 2; mt++)
#pragma unroll
    for (int dt = 0; dt < 4; dt++) oacc[mt][dt] = (f32x4){0.f, 0.f, 0.f, 0.f};
  float mx[2][4], li[2][4];
#pragma unroll
  for (int mt = 0; mt < 2; mt++)
#pragma unroll
    for (int rr = 0; rr < 4; rr++) { mx[mt][rr] = -1e30f; li[mt][rr] = 0.f; }

  const int kbase = n * QB - 256;
  for (int ch = -1; ch < 10; ch++) {
    const int kc = kbase + ch * 64;
    const bool isG = (ch < 0);
    __syncthreads();
    // ---- stage K (row-major) ----
    {
      const int key = tid >> 2, d0 = (tid & 3) * 16;
      const int kp = isG ? ((key == 0) ? 0 : -1) : kc + key;
      int4 a = make_int4(0, 0, 0, 0), c = make_int4(0, 0, 0, 0);
      if (kp >= 0 && kp < SS) {
        const unsigned short* src = kB + (headBase + kp) * 64 + d0;
        a = *reinterpret_cast<const int4*>(src);
        c = *reinterpret_cast<const int4*>(src + 8);
      }
      *reinterpret_cast<int4*>(&sK[key * 72 + d0]) = a;
      *reinterpret_cast<int4*>(&sK[key * 72 + d0 + 8]) = c;
    }
    // ---- stage V transposed ----
    {
      const int key = tid & 63, d0 = (tid >> 6) * 16;
      const int kp = isG ? ((key == 0) ? 0 : -1) : kc + key;
      int4 a = make_int4(0, 0, 0, 0), c = make_int4(0, 0, 0, 0);
      if (kp >= 0 && kp < SS) {
        const unsigned short* src = vB + (headBase + kp) * 64 + d0;
        a = *reinterpret_cast<const int4*>(src);
        c = *reinterpret_cast<const int4*>(src + 8);
      }
      unsigned short e[16];
      *reinterpret_cast<int4*>(&e[0]) = a;
      *reinterpret_cast<int4*>(&e[8]) = c;
#pragma unroll
      for (int j = 0; j < 16; j++) sVt[(d0 + j) * 72 + key] = e[j];
    }
    if (tid < 64) {
      int ok;
      if (isG) ok = (tid == 0) ? mask[(size_t)b * SS] : 0;
      else {
        const int kp = kc + tid;
        ok = (kp >= 1 && kp < SS) ? mask[(size_t)b * SS + kp] : 0;
      }
      sM[tid] = ok;
    }
    __syncthreads();

    // wave band skip (compute only; barriers stay uniform)
    if (!isG && (kc > qw0 + 31 + 256 || kc + 63 < qw0 - 256)) continue;

    // ---- QK^T ----
    f32x4 sacc[2][4];
#pragma unroll
    for (int mt = 0; mt < 2; mt++)
#pragma unroll
      for (int nt = 0; nt < 4; nt++) sacc[mt][nt] = (f32x4){0.f, 0.f, 0.f, 0.f};
#pragma unroll
    for (int kh = 0; kh < 2; kh++) {
      frag8 kf[4];
#pragma unroll
      for (int nt = 0; nt < 4; nt++)
        kf[nt] = *reinterpret_cast<const frag8*>(&sK[(nt * 16 + r16) * 72 + kh * 32 + quad * 8]);
#pragma unroll
      for (int mt = 0; mt < 2; mt++)
#pragma unroll
        for (int nt = 0; nt < 4; nt++)
          sacc[mt][nt] = __builtin_amdgcn_mfma_f32_16x16x32_bf16(qf[mt][kh], kf[nt], sacc[mt][nt], 0, 0, 0);
    }

    // ---- masking + online softmax ----
    int mreg[4];
#pragma unroll
    for (int nt = 0; nt < 4; nt++) mreg[nt] = sM[nt * 16 + r16];
    float al[2][4];
#pragma unroll
    for (int mt = 0; mt < 2; mt++) {
      float rmax[4] = {-1e30f, -1e30f, -1e30f, -1e30f};
#pragma unroll
      for (int nt = 0; nt < 4; nt++) {
        const int kp = isG ? 0 : kc + nt * 16 + r16;
#pragma unroll
        for (int rr = 0; rr < 4; rr++) {
          const int sq = qw0 + mt * 16 + quad * 4 + rr;
          const bool valid = (mreg[nt] != 0) && (isG || (unsigned)(kp - sq + 256) <= 512u);
          const float sv = valid ? sacc[mt][nt][rr] : -1e30f;
          sacc[mt][nt][rr] = sv;
          rmax[rr] = fmaxf(rmax[rr], sv);
        }
      }
#pragma unroll
      for (int rr = 0; rr < 4; rr++) {
#pragma unroll
        for (int off = 1; off < 16; off <<= 1)
          rmax[rr] = fmaxf(rmax[rr], __shfl_xor(rmax[rr], off, 64));
        const float mnew = fmaxf(mx[mt][rr], rmax[rr]);
        al[mt][rr] = __expf(mx[mt][rr] - mnew);
        mx[mt][rr] = mnew;
      }
      float rsum[4] = {0.f, 0.f, 0.f, 0.f};
#pragma unroll
      for (int nt = 0; nt < 4; nt++)
#pragma unroll
        for (int rr = 0; rr < 4; rr++) {
          const float sv = sacc[mt][nt][rr];
          const float p = (sv < -5e29f) ? 0.f : __expf(sv - mx[mt][rr]);
          rsum[rr] += p;
          sP[wave][(mt * 16 + quad * 4 + rr) * 72 + nt * 16 + r16] = f2b(p);
        }
#pragma unroll
      for (int rr = 0; rr < 4; rr++) {
#pragma unroll
        for (int off = 1; off < 16; off <<= 1) rsum[rr] += __shfl_xor(rsum[rr], off, 64);
        li[mt][rr] = li[mt][rr] * al[mt][rr] + rsum[rr];
      }
#pragma unroll
      for (int dt = 0; dt < 4; dt++)
#pragma unroll
        for (int rr = 0; rr < 4; rr++) oacc[mt][dt][rr] *= al[mt][rr];
    }

    // ---- PV (P from per-wave LDS, same-wave DS ops are in-order) ----
#pragma unroll
    for (int kh = 0; kh < 2; kh++) {
      frag8 pf[2], vf[4];
#pragma unroll
      for (int mt = 0; mt < 2; mt++)
        pf[mt] = *reinterpret_cast<const frag8*>(&sP[wave][(mt * 16 + r16) * 72 + kh * 32 + quad * 8]);
#pragma unroll
      for (int dt = 0; dt < 4; dt++)
        vf[dt] = *reinterpret_cast<const frag8*>(&sVt[(dt * 16 + r16) * 72 + kh * 32 + quad * 8]);
#pragma unroll
      for (int mt = 0; mt < 2; mt++)
#pragma unroll
        for (int dt = 0; dt < 4; dt++)
          oacc[mt][dt] = __builtin_amdgcn_mfma_f32_16x16x32_bf16(pf[mt], vf[dt], oacc[mt][dt], 0, 0, 0);
    }
  }

  // ---- epilogue ----
#pragma unroll
  for (int mt = 0; mt < 2; mt++) {
    float rli[4];
#pragma unroll
    for (int rr = 0; rr < 4; rr++) rli[rr] = 1.f / li[mt][rr];
#pragma unroll
    for (int dt = 0; dt < 4; dt++)
#pragma unroll
      for (int rr = 0; rr < 4; rr++) {
        const int sq = qw0 + mt * 16 + quad * 4 + rr;
        const int d = dt * 16 + r16;
        ctxB[((size_t)(b * SS + sq)) * DD + h * 64 + d] = f2b(oacc[mt][dt][rr] * rli[rr]);
      }
  }
}

// ---------- full attention for query 0: split-K phase 1 ----------
// grid (16, H, B), block 256: each block = 256-key chunk of one head.
// partials: part[((b*HH+h)*16 + ch)*68]: o[64], m, l
__global__ __launch_bounds__(256) void attn_r0_part(const unsigned short* __restrict__ qB,
                                                    const unsigned short* __restrict__ kB,
                                                    const unsigned short* __restrict__ vB,
                                                    const int* __restrict__ mask,
                                                    float* __restrict__ part) {
  const int ch = blockIdx.x, h = blockIdx.y, b = blockIdx.z;
  const int tid = threadIdx.x;
  const int lane = tid & 63, wave = tid >> 6;
  const size_t headBase = ((size_t)(b * HH + h)) * SS;

  __shared__ float sQ[64];
  __shared__ float wmx[4], wls[4];
  __shared__ float sO[4][64];
  if (tid < 8) {
    int4 t = *reinterpret_cast<const int4*>(qB + headBase * 64 + tid * 8);
    float f[8]; unpack8(t, f);
#pragma unroll
    for (int j = 0; j < 8; j++) sQ[tid * 8 + j] = f[j];
  }
  __syncthreads();

  const int key = ch * 256 + tid;
  // score = q . k
  float vreg[64];
  float sc;
  {
    float s = 0.f;
    const unsigned short* kp = kB + (headBase + key) * 64;
#pragma unroll
    for (int i = 0; i < 8; i++) {
      int4 t = *reinterpret_cast<const int4*>(kp + i * 8);
      float f[8]; unpack8(t, f);
#pragma unroll
      for (int j = 0; j < 8; j++) s = fmaf(sQ[i * 8 + j], f[j], s);
    }
    sc = (mask[(size_t)b * SS + key] != 0) ? s : -1e9f;
  }
  // block max
  float m = sc;
#pragma unroll
  for (int off = 1; off < 64; off <<= 1) m = fmaxf(m, __shfl_xor(m, off, 64));
  if (lane == 0) wmx[wave] = m;
  __syncthreads();
  const float Mx = fmaxf(fmaxf(wmx[0], wmx[1]), fmaxf(wmx[2], wmx[3]));
  const float p = __expf(sc - Mx);
  float ls = p;
#pragma unroll
  for (int off = 1; off < 64; off <<= 1) ls += __shfl_xor(ls, off, 64);
  // o = p * v
  {
    const unsigned short* vp = vB + (headBase + key) * 64;
#pragma unroll
    for (int i = 0; i < 8; i++) {
      int4 t = *reinterpret_cast<const int4*>(vp + i * 8);
      float f[8]; unpack8(t, f);
#pragma unroll
      for (int j = 0; j < 8; j++) vreg[i * 8 + j] = p * f[j];
    }
  }
  // wave butterfly reduce all 64 components
#pragma unroll
  for (int off = 1; off < 64; off <<= 1)
#pragma unroll
    for (int d = 0; d < 64; d++) vreg[d] += __shfl_xor(vreg[d], off, 64);
  if (lane == 0) {
    wls[wave] = ls;
#pragma unroll
    for (int d = 0; d < 64; d++) sO[wave][d] = vreg[d];
  }
  __syncthreads();
  if (tid < 64) {
    float* pp = part + ((size_t)((b * HH + h) * 16 + ch)) * 68;
    pp[tid] = sO[0][tid] + sO[1][tid] + sO[2][tid] + sO[3][tid];
    if (tid == 0) {
      pp[64] = Mx;
      pp[65] = wls[0] + wls[1] + wls[2] + wls[3];
    }
  }
}

// ---------- phase 2: combine 16 chunk partials, overwrite ctx row 0 ----------
__global__ __launch_bounds__(64) void attn_r0_comb(const float* __restrict__ part,
                                                   unsigned short* __restrict__ ctxB) {
  const int h = blockIdx.x, b = blockIdx.y;
  const int tid = threadIdx.x;
  const float* base = part + ((size_t)((b * HH + h) * 16)) * 68;
  float M = -1e30f;
#pragma unroll
  for (int c = 0; c < 16; c++) M = fmaxf(M, base[c * 68 + 64]);
  float L = 0.f, o = 0.f;
#pragma unroll
  for (int c = 0; c < 16; c++) {
    const float w = __expf(base[c * 68 + 64] - M);
    L += base[c * 68 + 65] * w;
    o = fmaf(w, base[c * 68 + tid], o);
  }
  ctxB[((size_t)(b * SS)) * DD + h * 64 + tid] = f2b(o / L);
}

// ---------- classifier ----------
__global__ __launch_bounds__(256) void cls_head(const float* __restrict__ h32,
                                                const float* __restrict__ W,
                                                const float* __restrict__ bc,
                                                float* __restrict__ out) {
  const int b = blockIdx.x;
  const float* hr = h32 + (size_t)b * SS * DD;
  float p0 = 0.f, p1 = 0.f, p2 = 0.f;
  for (int d = threadIdx.x; d < DD; d += 256) {
    const float x = hr[d];
    p0 = fmaf(x, W[d * 3 + 0], p0);
    p1 = fmaf(x, W[d * 3 + 1], p1);
    p2 = fmaf(x, W[d * 3 + 2], p2);
  }
  __shared__ float r0[256], r1[256], r2[256];
  r0[threadIdx.x] = p0; r1[threadIdx.x] = p1; r2[threadIdx.x] = p2;
  __syncthreads();
  if (threadIdx.x == 0) {
    float s0 = 0.f, s1 = 0.f, s2 = 0.f;
    for (int t = 0; t < 256; t++) { s0 += r0[t]; s1 += r1[t]; s2 += r2[t]; }
    out[b * 3 + 0] = s0 + bc[0];
    out[b * 3 + 1] = s1 + bc[1];
    out[b * 3 + 2] = s2 + bc[2];
  }
}

// ---------- workspace layout (bytes) ----------
static const size_t OFF_WT = 0;             // transposed weights, bf16
static const size_t OFF_H32 = 28311552;     // MM*DD fp32
static const size_t OFF_HB = 53477376;      // MM*DD bf16
static const size_t OFF_Q = 66060288;       // B*H*S*DH bf16
static const size_t OFF_K = 78643200;
static const size_t OFF_V = 91226112;
static const size_t OFF_CTX = 103809024;    // MM*DD bf16
static const size_t OFF_DELTA = 116391936;  // MM*DD fp32 (also: attn row0 partials)
static const size_t OFF_F1 = 141557760;     // MM*FF bf16
static const size_t WS_NEEDED = 191889408;

extern "C" void kernel_launch(void* const* d_in, const int* in_sizes, int n_in,
                              void* d_out, int out_size, void* d_ws, size_t ws_size,
                              hipStream_t stream) {
  (void)in_sizes; (void)n_in; (void)out_size;
  if (ws_size < WS_NEEDED) return;

  const int* ids = (const int*)d_in[0];
  const int* mask = (const int*)d_in[1];
  const float* emb_tok = (const float*)d_in[2];
  const float* emb_pos = (const float*)d_in[3];
  const float* eg = (const float*)d_in[4];
  const float* eb = (const float*)d_in[5];
  const float* Wq = (const float*)d_in[6];
  const float* bq = (const float*)d_in[7];
  const float* Wk = (const float*)d_in[8];
  const float* bk = (const float*)d_in[9];
  const float* Wv = (const float*)d_in[10];
  const float* bv = (const float*)d_in[11];
  const float* Wo = (const float*)d_in[12];
  const float* bo = (const float*)d_in[13];
  const float* ln1g = (const float*)d_in[14];
  const float* ln1b = (const float*)d_in[15];
  const float* W1 = (const float*)d_in[16];
  const float* b1 = (const float*)d_in[17];
  const float* W2 = (const float*)d_in[18];
  const float* b2 = (const float*)d_in[19];
  const float* ln2g = (const float*)d_in[20];
  const float* ln2b = (const float*)d_in[21];
  const float* clsW = (const float*)d_in[22];
  const float* clsb = (const float*)d_in[23];
  float* out = (float*)d_out;

  char* ws = (char*)d_ws;
  unsigned short* wt = (unsigned short*)(ws + OFF_WT);
  float* h32 = (float*)(ws + OFF_H32);
  unsigned short* hB = (unsigned short*)(ws + OFF_HB);
  unsigned short* qb16 = (unsigned short*)(ws + OFF_Q);
  unsigned short* kb16 = (unsigned short*)(ws + OFF_K);
  unsigned short* vb16 = (unsigned short*)(ws + OFF_V);
  unsigned short* ctxB = (unsigned short*)(ws + OFF_CTX);
  float* delta = (float*)(ws + OFF_DELTA);
  unsigned short* f1B = (unsigned short*)(ws + OFF_F1);

  for (int l = 0; l < 2; l++) {
    const size_t lw = (size_t)l * 7077888;
    transpose_bf16<<<dim3(24, 24), dim3(32, 8), 0, stream>>>(Wq + (size_t)l * 589824, wt + lw + 0, 768, 768);
    transpose_bf16<<<dim3(24, 24), dim3(32, 8), 0, stream>>>(Wk + (size_t)l * 589824, wt + lw + 589824, 768, 768);
    transpose_bf16<<<dim3(24, 24), dim3(32, 8), 0, stream>>>(Wv + (size_t)l * 589824, wt + lw + 1179648, 768, 768);
    transpose_bf16<<<dim3(24, 24), dim3(32, 8), 0, stream>>>(Wo + (size_t)l * 589824, wt + lw + 1769472, 768, 768);
    transpose_bf16<<<dim3(96, 24), dim3(32, 8), 0, stream>>>(W1 + (size_t)l * 2359296, wt + lw + 2359296, 768, 3072);
    transpose_bf16<<<dim3(24, 96), dim3(32, 8), 0, stream>>>(W2 + (size_t)l * 2359296, wt + lw + 4718592, 3072, 768);
  }

  embed_ln<<<MM, 256, 0, stream>>>(ids, emb_tok, emb_pos, eg, eb, h32, hB);

  for (int l = 0; l < 2; l++) {
    const size_t lw = (size_t)l * 7077888;
    gemm_nt<1><<<dim3(18, 64), 256, 0, stream>>>(hB, wt + lw, bq + l * 768, bk + l * 768,
                                                 bv + l * 768, nullptr, qb16, kb16, vb16,
                                                 MM, 2304, 768);
    attn_win<<<dim3(SS / QB, 12, 2), 256, 0, stream>>>(qb16, kb16, vb16, mask, ctxB);
    attn_r0_part<<<dim3(16, 12, 2), 256, 0, stream>>>(qb16, kb16, vb16, mask, delta);
    attn_r0_comb<<<dim3(12, 2), 64, 0, stream>>>(delta, ctxB);
    gemm_nt<0><<<dim3(6, 64), 256, 0, stream>>>(ctxB, wt + lw + 1769472, bo + l * 768, nullptr,
                                                nullptr, delta, nullptr, nullptr, nullptr,
                                                MM, 768, 768);
    ln_res<<<MM, 256, 0, stream>>>(h32, delta, ln1g + l * 768, ln1b + l * 768, hB);
    gemm_nt<2><<<dim3(24, 64), 256, 0, stream>>>(hB, wt + lw + 2359296, b1 + l * 3072, nullptr,
                                                 nullptr, nullptr, f1B, nullptr, nullptr,
                                                 MM, 3072, 768);
    gemm_nt<0><<<dim3(6, 64), 256, 0, stream>>>(f1B, wt + lw + 4718592, b2 + l * 768, nullptr,
                                                nullptr, delta, nullptr, nullptr, nullptr,
                                                MM, 768, 3072);
    ln_res<<<MM, 256, 0, stream>>>(h32, delta, ln2g + l * 768, ln2b + l * 768, hB);
  }

  cls_head<<<dim3(BB), 256, 0, stream>>>(h32, clsW, clsb, out);
}

// Round 4
// 980.837 us; speedup vs baseline: 2.3396x; 1.0502x over previous
//
#include <hip/hip_runtime.h>
#include <math.h>

#define BB 2
#define SS 4096
#define DD 768
#define HH 12
#define LL 2
#define FF 3072
#define CC 256
#define MM 8192   // B*S
#define QB 128    // queries per attention block
#define QKVN 2304 // fused QKV row width

using frag8 = __attribute__((ext_vector_type(8))) short;   // 8 bf16
using f32x4 = __attribute__((ext_vector_type(4))) float;

// ---------- helpers ----------
__device__ __forceinline__ unsigned short f2b(float f) {
  unsigned u = __float_as_uint(f);
  u = u + 0x7fffu + ((u >> 16) & 1u);   // RNE
  return (unsigned short)(u >> 16);
}
__device__ __forceinline__ unsigned pack2(float a, float b) {
  return (unsigned)f2b(a) | ((unsigned)f2b(b) << 16);
}
__device__ __forceinline__ float b2f(unsigned short v) {
  return __uint_as_float(((unsigned)v) << 16);
}
__device__ __forceinline__ void unpack8(int4 t, float* f) {
  unsigned u;
  u = (unsigned)t.x; f[0] = __uint_as_float(u << 16); f[1] = __uint_as_float(u & 0xffff0000u);
  u = (unsigned)t.y; f[2] = __uint_as_float(u << 16); f[3] = __uint_as_float(u & 0xffff0000u);
  u = (unsigned)t.z; f[4] = __uint_as_float(u << 16); f[5] = __uint_as_float(u & 0xffff0000u);
  u = (unsigned)t.w; f[6] = __uint_as_float(u << 16); f[7] = __uint_as_float(u & 0xffff0000u);
}
__device__ __forceinline__ void reduce2(float& s1, float& s2) {
#pragma unroll
  for (int off = 32; off > 0; off >>= 1) {
    s1 += __shfl_down(s1, off);
    s2 += __shfl_down(s2, off);
  }
  __shared__ float r1[4], r2[4];
  const int lane = threadIdx.x & 63, wv = threadIdx.x >> 6;
  if (lane == 0) { r1[wv] = s1; r2[wv] = s2; }
  __syncthreads();
  s1 = r1[0] + r1[1] + r1[2] + r1[3];
  s2 = r2[0] + r2[1] + r2[2] + r2[3];
  __syncthreads();
}
// async global->LDS, 16B per lane; lds dest = wave-uniform base + lane*16
__device__ __forceinline__ void async16(const unsigned short* g, unsigned short* l) {
  __builtin_amdgcn_global_load_lds((__attribute__((address_space(1))) void*)(g),
                                   (__attribute__((address_space(3))) void*)(l), 16, 0, 0);
}

// ---------- weight transpose fp32(K,N) -> bf16(N,K) ----------
__global__ __launch_bounds__(256) void transpose_bf16(const float* __restrict__ in,
                                                      unsigned short* __restrict__ out,
                                                      int K, int N) {
  __shared__ float t[32][33];
  const int n0 = blockIdx.x * 32, k0 = blockIdx.y * 32;
  const int tx = threadIdx.x, ty = threadIdx.y;   // block (32,8)
#pragma unroll
  for (int i = 0; i < 32; i += 8) t[ty + i][tx] = in[(size_t)(k0 + ty + i) * N + n0 + tx];
  __syncthreads();
#pragma unroll
  for (int i = 0; i < 32; i += 8) out[(size_t)(n0 + ty + i) * K + k0 + tx] = f2b(t[tx][ty + i]);
}

// ---------- embedding + LN ----------
__global__ __launch_bounds__(256) void embed_ln(const int* __restrict__ ids,
                                                const float* __restrict__ etok,
                                                const float* __restrict__ epos,
                                                const float* __restrict__ g,
                                                const float* __restrict__ bb,
                                                float* __restrict__ h32,
                                                unsigned short* __restrict__ hB) {
  const int row = blockIdx.x;
  const int s = row & (SS - 1);
  const int id = ids[row];
  float x[3];
#pragma unroll
  for (int i = 0; i < 3; i++) {
    int j = threadIdx.x + i * 256;
    x[i] = etok[(size_t)id * DD + j] + epos[(size_t)s * DD + j];
  }
  float s1 = x[0] + x[1] + x[2];
  float s2 = x[0] * x[0] + x[1] * x[1] + x[2] * x[2];
  reduce2(s1, s2);
  const float mean = s1 * (1.f / 768.f);
  const float var = s2 * (1.f / 768.f) - mean * mean;
  const float rs = rsqrtf(var + 1e-5f);
#pragma unroll
  for (int i = 0; i < 3; i++) {
    int j = threadIdx.x + i * 256;
    float y = (x[i] - mean) * rs * g[j] + bb[j];
    h32[(size_t)row * DD + j] = y;
    hB[(size_t)row * DD + j] = f2b(y);
  }
}

// ---------- residual + LN ----------
__global__ __launch_bounds__(256) void ln_res(float* __restrict__ h32,
                                              const float* __restrict__ delta,
                                              const float* __restrict__ g,
                                              const float* __restrict__ bb,
                                              unsigned short* __restrict__ hB) {
  const int row = blockIdx.x;
  float x[3];
#pragma unroll
  for (int i = 0; i < 3; i++) {
    int j = threadIdx.x + i * 256;
    x[i] = h32[(size_t)row * DD + j] + delta[(size_t)row * DD + j];
  }
  float s1 = x[0] + x[1] + x[2];
  float s2 = x[0] * x[0] + x[1] * x[1] + x[2] * x[2];
  reduce2(s1, s2);
  const float mean = s1 * (1.f / 768.f);
  const float var = s2 * (1.f / 768.f) - mean * mean;
  const float rs = rsqrtf(var + 1e-5f);
#pragma unroll
  for (int i = 0; i < 3; i++) {
    int j = threadIdx.x + i * 256;
    float y = (x[i] - mean) * rs * g[j] + bb[j];
    h32[(size_t)row * DD + j] = y;
    hB[(size_t)row * DD + j] = f2b(y);
  }
}

// ---------- bf16 MFMA GEMM:  C(M,N) = A(M,K) @ Bt(N,K)^T + bias ----------
// EPI 0: fp32 row-major (outF, bias0)
// EPI 1: QKV row-major bf16 [M][2304], q-segment scaled 0.125; bias segment block-uniform
// EPI 2: tanh-GELU -> bf16 row-major (oq, bias0)
template <int EPI>
__global__ __launch_bounds__(256) void gemm_nt(const unsigned short* __restrict__ A,
                                               const unsigned short* __restrict__ Bt,
                                               const float* __restrict__ bias0,
                                               const float* __restrict__ bias1,
                                               const float* __restrict__ bias2,
                                               float* __restrict__ outF,
                                               unsigned short* __restrict__ oq,
                                               int M, int N, int K) {
  __shared__ unsigned short sA[128 * 32];
  __shared__ unsigned short sB[128 * 32];
  const int tid = threadIdx.x;
  const int m0 = blockIdx.y * 128, n0 = blockIdx.x * 128;
  const int wave = tid >> 6, lane = tid & 63;
  const int wm = (wave >> 1) * 64, wn = (wave & 1) * 64;
  const int quad = lane >> 4, r16 = lane & 15;

  // staging: wave w covers rows [w*32, w*32+32) in two 16-row issues
  const int srow = wave * 32 + (lane >> 2);
  const int scol = (lane & 3) * 8;
  const unsigned short* gA0 = A + (size_t)(m0 + srow) * K + scol;
  const unsigned short* gA1 = gA0 + (size_t)16 * K;
  const unsigned short* gB0 = Bt + (size_t)(n0 + srow) * K + scol;
  const unsigned short* gB1 = gB0 + (size_t)16 * K;
  unsigned short* lA0 = &sA[(wave * 32) * 32];
  unsigned short* lA1 = &sA[(wave * 32 + 16) * 32];
  unsigned short* lB0 = &sB[(wave * 32) * 32];
  unsigned short* lB1 = &sB[(wave * 32 + 16) * 32];

  f32x4 acc[4][4];
#pragma unroll
  for (int i = 0; i < 4; i++)
#pragma unroll
    for (int j = 0; j < 4; j++) acc[i][j] = (f32x4){0.f, 0.f, 0.f, 0.f};

  const int kiters = K >> 5;
  for (int kt = 0; kt < kiters; kt++) {
    const int k0 = kt << 5;
    __syncthreads();
    async16(gA0 + k0, lA0);
    async16(gA1 + k0, lA1);
    async16(gB0 + k0, lB0);
    async16(gB1 + k0, lB1);
    __syncthreads();   // drains vmcnt(0)
    frag8 af[4], bf[4];
#pragma unroll
    for (int i = 0; i < 4; i++)
      af[i] = *reinterpret_cast<const frag8*>(&sA[(wm + i * 16 + r16) * 32 + quad * 8]);
#pragma unroll
    for (int j = 0; j < 4; j++)
      bf[j] = *reinterpret_cast<const frag8*>(&sB[(wn + j * 16 + r16) * 32 + quad * 8]);
#pragma unroll
    for (int i = 0; i < 4; i++)
#pragma unroll
      for (int j = 0; j < 4; j++)
        acc[i][j] = __builtin_amdgcn_mfma_f32_16x16x32_bf16(af[i], bf[j], acc[i][j], 0, 0, 0);
  }

  // EPI1 block-uniform segment select (N=2304, 768 = 6 x 128-tiles)
  const int which = (EPI == 1) ? (n0 / 768) : 0;
  const float* bw = (EPI == 1) ? ((which == 0) ? bias0 : (which == 1) ? bias1 : bias2) : bias0;
  const float qsc = (EPI == 1 && which == 0) ? 0.125f : 1.f;
  const int cofs = which * 768;

#pragma unroll
  for (int i = 0; i < 4; i++)
#pragma unroll
    for (int j = 0; j < 4; j++)
#pragma unroll
      for (int rr = 0; rr < 4; rr++) {
        const int row = m0 + wm + i * 16 + quad * 4 + rr;
        const int col = n0 + wn + j * 16 + r16;
        if (EPI == 0) {
          outF[(size_t)row * N + col] = acc[i][j][rr] + bias0[col];
        } else if (EPI == 1) {
          float v = (acc[i][j][rr] + bw[col - cofs]) * qsc;
          oq[(size_t)row * N + col] = f2b(v);
        } else {
          float v = acc[i][j][rr] + bias0[col];
          // tanh-GELU: v * sigmoid(2*0.7978845608*(v + 0.044715 v^3))
          float y = 1.5957691216f * (v + 0.044715f * v * v * v);
          float ge = v / (1.f + __expf(-y));
          oq[(size_t)row * N + col] = f2b(ge);
        }
      }
}

// ---------- MFMA flash sliding-window attention (transposed scores) ----------
// block = 256 thr (4 waves), handles QB=128 queries of (b,h); wave owns 32.
// S^T = K.Q^T  => C-layout: col(r16)=query, row(quad*4+rr)=key  => per-lane softmax state.
// O^T = V^T.P  => C-layout: col(r16)=query, row=d  => packed epilogue stores.
__global__ __launch_bounds__(256) void attn_win(const unsigned short* __restrict__ qkv,
                                                const int* __restrict__ mask,
                                                unsigned short* __restrict__ ctxB) {
  const int n = blockIdx.x, h = blockIdx.y, b = blockIdx.z;
  const int tid = threadIdx.x;
  const int wave = tid >> 6, lane = tid & 63;
  const int quad = lane >> 4, r16 = lane & 15;
  const size_t rowB = (size_t)(b * SS);

  __shared__ unsigned short sK[64 * 72];        // keys x d, stride 72
  __shared__ unsigned short sVt[64 * 72];       // d x keys, stride 72
  __shared__ unsigned short sP2[4][32 * 72];    // per-wave P^T: [q_local][key], stride 72
  __shared__ __align__(16) int sM[64];

  const int qw0 = n * QB + wave * 32;

  // Q fragments (B-operand): lane r16 -> q, quad*8+j -> d
  frag8 qf[2][2];
#pragma unroll
  for (int mt = 0; mt < 2; mt++)
#pragma unroll
    for (int kh = 0; kh < 2; kh++) {
      int4 t = *reinterpret_cast<const int4*>(
          qkv + (rowB + qw0 + mt * 16 + r16) * QKVN + h * 64 + kh * 32 + quad * 8);
      qf[mt][kh] = *reinterpret_cast<frag8*>(&t);
    }

  f32x4 oacc[4][2];   // [dt][mt]
#pragma unroll
  for (int dt = 0; dt < 4; dt++)
#pragma unroll
    for (int mt = 0; mt < 2; mt++) oacc[dt][mt] = (f32x4){0.f, 0.f, 0.f, 0.f};
  float mx[2], li[2];
#pragma unroll
  for (int mt = 0; mt < 2; mt++) { mx[mt] = -1e30f; li[mt] = 0.f; }

  const int kbase = n * QB - 256;
  for (int ch = -1; ch < 10; ch++) {
    const int kc = kbase + ch * 64;
    const bool isG = (ch < 0);
    __syncthreads();
    // ---- stage K (row-major) ----
    {
      const int key = tid >> 2, d0 = (tid & 3) * 16;
      const int kp = isG ? ((key == 0) ? 0 : -1) : kc + key;
      int4 a = make_int4(0, 0, 0, 0), c = make_int4(0, 0, 0, 0);
      if (kp >= 0 && kp < SS) {
        const unsigned short* src = qkv + (rowB + kp) * QKVN + 768 + h * 64 + d0;
        a = *reinterpret_cast<const int4*>(src);
        c = *reinterpret_cast<const int4*>(src + 8);
      }
      *reinterpret_cast<int4*>(&sK[key * 72 + d0]) = a;
      *reinterpret_cast<int4*>(&sK[key * 72 + d0 + 8]) = c;
    }
    // ---- stage V transposed ----
    {
      const int key = tid & 63, d0 = (tid >> 6) * 16;
      const int kp = isG ? ((key == 0) ? 0 : -1) : kc + key;
      int4 a = make_int4(0, 0, 0, 0), c = make_int4(0, 0, 0, 0);
      if (kp >= 0 && kp < SS) {
        const unsigned short* src = qkv + (rowB + kp) * QKVN + 1536 + h * 64 + d0;
        a = *reinterpret_cast<const int4*>(src);
        c = *reinterpret_cast<const int4*>(src + 8);
      }
      unsigned short e[16];
      *reinterpret_cast<int4*>(&e[0]) = a;
      *reinterpret_cast<int4*>(&e[8]) = c;
#pragma unroll
      for (int j = 0; j < 16; j++) sVt[(d0 + j) * 72 + key] = e[j];
    }
    if (tid < 64) {
      int ok;
      if (isG) ok = (tid == 0) ? mask[rowB] : 0;
      else {
        const int kp = kc + tid;
        ok = (kp >= 1 && kp < SS) ? mask[rowB + kp] : 0;
      }
      sM[tid] = ok;
    }
    __syncthreads();

    // wave band skip (compute only; barriers stay uniform)
    if (!isG && (kc > qw0 + 31 + 256 || kc + 63 < qw0 - 256)) continue;

    // ---- S^T = K.Q^T ----
    f32x4 sacc[4][2];   // [nt][mt]: row=key part, col=q
#pragma unroll
    for (int nt = 0; nt < 4; nt++)
#pragma unroll
      for (int mt = 0; mt < 2; mt++) sacc[nt][mt] = (f32x4){0.f, 0.f, 0.f, 0.f};
#pragma unroll
    for (int kh = 0; kh < 2; kh++) {
      frag8 kf[4];
#pragma unroll
      for (int nt = 0; nt < 4; nt++)
        kf[nt] = *reinterpret_cast<const frag8*>(&sK[(nt * 16 + r16) * 72 + kh * 32 + quad * 8]);
#pragma unroll
      for (int nt = 0; nt < 4; nt++)
#pragma unroll
        for (int mt = 0; mt < 2; mt++)
          sacc[nt][mt] = __builtin_amdgcn_mfma_f32_16x16x32_bf16(kf[nt], qf[mt][kh], sacc[nt][mt], 0, 0, 0);
    }

    // mask bits per key row (same for both mt)
    int mv[4][4];
#pragma unroll
    for (int nt = 0; nt < 4; nt++) {
      int4 t = *reinterpret_cast<const int4*>(&sM[nt * 16 + quad * 4]);
      mv[nt][0] = t.x; mv[nt][1] = t.y; mv[nt][2] = t.z; mv[nt][3] = t.w;
    }

    // ---- per-lane online softmax (q on r16) ----
#pragma unroll
    for (int mt = 0; mt < 2; mt++) {
      const int qg = qw0 + mt * 16 + r16;
      float m_c = -1e30f;
#pragma unroll
      for (int nt = 0; nt < 4; nt++)
#pragma unroll
        for (int rr = 0; rr < 4; rr++) {
          const int kp = kc + nt * 16 + quad * 4 + rr;
          const bool valid = (mv[nt][rr] != 0) && (isG || (unsigned)(kp - qg + 256) <= 512u);
          const float s = valid ? sacc[nt][mt][rr] : -1e30f;
          sacc[nt][mt][rr] = s;
          m_c = fmaxf(m_c, s);
        }
      m_c = fmaxf(m_c, __shfl_xor(m_c, 16, 64));
      m_c = fmaxf(m_c, __shfl_xor(m_c, 32, 64));
      const float mnew = fmaxf(mx[mt], m_c);
      const float alpha = __expf(mx[mt] - mnew);
      mx[mt] = mnew;
      float s_c = 0.f;
#pragma unroll
      for (int nt = 0; nt < 4; nt++) {
        float pk[4];
#pragma unroll
        for (int rr = 0; rr < 4; rr++) {
          const float sv = sacc[nt][mt][rr];
          float p = __expf(sv - mnew);
          p = (sv > -5e29f) ? p : 0.f;
          s_c += p;
          pk[rr] = p;
        }
        uint2 w;
        w.x = pack2(pk[0], pk[1]);
        w.y = pack2(pk[2], pk[3]);
        *reinterpret_cast<uint2*>(&sP2[wave][(mt * 16 + r16) * 72 + nt * 16 + quad * 4]) = w;
      }
      s_c += __shfl_xor(s_c, 16, 64);
      s_c += __shfl_xor(s_c, 32, 64);
      li[mt] = li[mt] * alpha + s_c;
#pragma unroll
      for (int dt = 0; dt < 4; dt++)
#pragma unroll
        for (int rr = 0; rr < 4; rr++) oacc[dt][mt][rr] *= alpha;
    }

    // ---- O^T += V^T.P (same-wave LDS, in-order) ----
#pragma unroll
    for (int kh = 0; kh < 2; kh++) {
      frag8 vf[4], pf[2];
#pragma unroll
      for (int dt = 0; dt < 4; dt++)
        vf[dt] = *reinterpret_cast<const frag8*>(&sVt[(dt * 16 + r16) * 72 + kh * 32 + quad * 8]);
#pragma unroll
      for (int mt = 0; mt < 2; mt++)
        pf[mt] = *reinterpret_cast<const frag8*>(&sP2[wave][(mt * 16 + r16) * 72 + kh * 32 + quad * 8]);
#pragma unroll
      for (int dt = 0; dt < 4; dt++)
#pragma unroll
        for (int mt = 0; mt < 2; mt++)
          oacc[dt][mt] = __builtin_amdgcn_mfma_f32_16x16x32_bf16(vf[dt], pf[mt], oacc[dt][mt], 0, 0, 0);
    }
  }

  // ---- epilogue: packed 8B stores ----
#pragma unroll
  for (int mt = 0; mt < 2; mt++) {
    const float inv = 1.f / li[mt];
    const int qg = qw0 + mt * 16 + r16;
#pragma unroll
    for (int dt = 0; dt < 4; dt++) {
      uint2 w;
      w.x = pack2(oacc[dt][mt][0] * inv, oacc[dt][mt][1] * inv);
      w.y = pack2(oacc[dt][mt][2] * inv, oacc[dt][mt][3] * inv);
      *reinterpret_cast<uint2*>(ctxB + (rowB + qg) * DD + h * 64 + dt * 16 + quad * 4) = w;
    }
  }
}

// ---------- full attention for query 0: split-K phase 1 ----------
// grid (16, H, B), block 256: each block = 256-key chunk of one head.
// partials: part[((b*HH+h)*16 + ch)*68]: o[64], m, l
__global__ __launch_bounds__(256) void attn_r0_part(const unsigned short* __restrict__ qkv,
                                                    const int* __restrict__ mask,
                                                    float* __restrict__ part) {
  const int ch = blockIdx.x, h = blockIdx.y, b = blockIdx.z;
  const int tid = threadIdx.x;
  const int lane = tid & 63, wave = tid >> 6;
  const size_t rowB = (size_t)(b * SS);

  __shared__ float sQ[64];
  __shared__ float wmx[4], wls[4];
  __shared__ float sPp[256];
  __shared__ float sO[4][64];
  if (tid < 8) {
    int4 t = *reinterpret_cast<const int4*>(qkv + rowB * QKVN + h * 64 + tid * 8);
    float f[8]; unpack8(t, f);
#pragma unroll
    for (int j = 0; j < 8; j++) sQ[tid * 8 + j] = f[j];
  }
  __syncthreads();

  const int key = ch * 256 + tid;
  float sc;
  {
    float s = 0.f;
    const unsigned short* kp = qkv + (rowB + key) * QKVN + 768 + h * 64;
#pragma unroll
    for (int i = 0; i < 8; i++) {
      int4 t = *reinterpret_cast<const int4*>(kp + i * 8);
      float f[8]; unpack8(t, f);
#pragma unroll
      for (int j = 0; j < 8; j++) s = fmaf(sQ[i * 8 + j], f[j], s);
    }
    sc = (mask[rowB + key] != 0) ? s : -1e9f;
  }
  float m = sc;
#pragma unroll
  for (int off = 1; off < 64; off <<= 1) m = fmaxf(m, __shfl_xor(m, off, 64));
  if (lane == 0) wmx[wave] = m;
  __syncthreads();
  const float Mx = fmaxf(fmaxf(wmx[0], wmx[1]), fmaxf(wmx[2], wmx[3]));
  const float p = __expf(sc - Mx);
  float ls = p;
#pragma unroll
  for (int off = 1; off < 64; off <<= 1) ls += __shfl_xor(ls, off, 64);
  sPp[tid] = p;
  if (lane == 0) wls[wave] = ls;
  __syncthreads();

  // per-wave matvec over its 64 keys; lane owns output dim d
  float acc = 0.f;
  const unsigned short* vb = qkv + (rowB + ch * 256 + wave * 64) * QKVN + 1536 + h * 64 + lane;
#pragma unroll 4
  for (int t = 0; t < 64; t++)
    acc = fmaf(sPp[wave * 64 + t], b2f(vb[(size_t)t * QKVN]), acc);
  sO[wave][lane] = acc;
  __syncthreads();
  if (tid < 64) {
    float* pp = part + ((size_t)((b * HH + h) * 16 + ch)) * 68;
    pp[tid] = sO[0][tid] + sO[1][tid] + sO[2][tid] + sO[3][tid];
    if (tid == 0) {
      pp[64] = Mx;
      pp[65] = wls[0] + wls[1] + wls[2] + wls[3];
    }
  }
}

// ---------- phase 2: combine 16 chunk partials, overwrite ctx row 0 ----------
__global__ __launch_bounds__(64) void attn_r0_comb(const float* __restrict__ part,
                                                   unsigned short* __restrict__ ctxB) {
  const int h = blockIdx.x, b = blockIdx.y;
  const int tid = threadIdx.x;
  const float* base = part + ((size_t)((b * HH + h) * 16)) * 68;
  float M = -1e30f;
#pragma unroll
  for (int c = 0; c < 16; c++) M = fmaxf(M, base[c * 68 + 64]);
  float L = 0.f, o = 0.f;
#pragma unroll
  for (int c = 0; c < 16; c++) {
    const float w = __expf(base[c * 68 + 64] - M);
    L += base[c * 68 + 65] * w;
    o = fmaf(w, base[c * 68 + tid], o);
  }
  ctxB[((size_t)(b * SS)) * DD + h * 64 + tid] = f2b(o / L);
}

// ---------- classifier ----------
__global__ __launch_bounds__(256) void cls_head(const float* __restrict__ h32,
                                                const float* __restrict__ W,
                                                const float* __restrict__ bc,
                                                float* __restrict__ out) {
  const int b = blockIdx.x;
  const float* hr = h32 + (size_t)b * SS * DD;
  float p0 = 0.f, p1 = 0.f, p2 = 0.f;
  for (int d = threadIdx.x; d < DD; d += 256) {
    const float x = hr[d];
    p0 = fmaf(x, W[d * 3 + 0], p0);
    p1 = fmaf(x, W[d * 3 + 1], p1);
    p2 = fmaf(x, W[d * 3 + 2], p2);
  }
  __shared__ float r0[256], r1[256], r2[256];
  r0[threadIdx.x] = p0; r1[threadIdx.x] = p1; r2[threadIdx.x] = p2;
  __syncthreads();
  if (threadIdx.x == 0) {
    float s0 = 0.f, s1 = 0.f, s2 = 0.f;
    for (int t = 0; t < 256; t++) { s0 += r0[t]; s1 += r1[t]; s2 += r2[t]; }
    out[b * 3 + 0] = s0 + bc[0];
    out[b * 3 + 1] = s1 + bc[1];
    out[b * 3 + 2] = s2 + bc[2];
  }
}

// ---------- workspace layout (bytes) ----------
static const size_t OFF_WT = 0;             // transposed weights, bf16
static const size_t OFF_H32 = 28311552;     // MM*DD fp32
static const size_t OFF_HB = 53477376;      // MM*DD bf16
static const size_t OFF_QKV = 66060288;     // MM*2304 bf16 (row-major fused QKV)
static const size_t OFF_CTX = 103809024;    // MM*DD bf16
static const size_t OFF_DELTA = 116391936;  // MM*DD fp32 (also: attn row0 partials)
static const size_t OFF_F1 = 141557760;     // MM*FF bf16
static const size_t WS_NEEDED = 191889408;

extern "C" void kernel_launch(void* const* d_in, const int* in_sizes, int n_in,
                              void* d_out, int out_size, void* d_ws, size_t ws_size,
                              hipStream_t stream) {
  (void)in_sizes; (void)n_in; (void)out_size;
  if (ws_size < WS_NEEDED) return;

  const int* ids = (const int*)d_in[0];
  const int* mask = (const int*)d_in[1];
  const float* emb_tok = (const float*)d_in[2];
  const float* emb_pos = (const float*)d_in[3];
  const float* eg = (const float*)d_in[4];
  const float* eb = (const float*)d_in[5];
  const float* Wq = (const float*)d_in[6];
  const float* bq = (const float*)d_in[7];
  const float* Wk = (const float*)d_in[8];
  const float* bk = (const float*)d_in[9];
  const float* Wv = (const float*)d_in[10];
  const float* bv = (const float*)d_in[11];
  const float* Wo = (const float*)d_in[12];
  const float* bo = (const float*)d_in[13];
  const float* ln1g = (const float*)d_in[14];
  const float* ln1b = (const float*)d_in[15];
  const float* W1 = (const float*)d_in[16];
  const float* b1 = (const float*)d_in[17];
  const float* W2 = (const float*)d_in[18];
  const float* b2 = (const float*)d_in[19];
  const float* ln2g = (const float*)d_in[20];
  const float* ln2b = (const float*)d_in[21];
  const float* clsW = (const float*)d_in[22];
  const float* clsb = (const float*)d_in[23];
  float* out = (float*)d_out;

  char* ws = (char*)d_ws;
  unsigned short* wt = (unsigned short*)(ws + OFF_WT);
  float* h32 = (float*)(ws + OFF_H32);
  unsigned short* hB = (unsigned short*)(ws + OFF_HB);
  unsigned short* qkvB = (unsigned short*)(ws + OFF_QKV);
  unsigned short* ctxB = (unsigned short*)(ws + OFF_CTX);
  float* delta = (float*)(ws + OFF_DELTA);
  unsigned short* f1B = (unsigned short*)(ws + OFF_F1);

  for (int l = 0; l < 2; l++) {
    const size_t lw = (size_t)l * 7077888;
    transpose_bf16<<<dim3(24, 24), dim3(32, 8), 0, stream>>>(Wq + (size_t)l * 589824, wt + lw + 0, 768, 768);
    transpose_bf16<<<dim3(24, 24), dim3(32, 8), 0, stream>>>(Wk + (size_t)l * 589824, wt + lw + 589824, 768, 768);
    transpose_bf16<<<dim3(24, 24), dim3(32, 8), 0, stream>>>(Wv + (size_t)l * 589824, wt + lw + 1179648, 768, 768);
    transpose_bf16<<<dim3(24, 24), dim3(32, 8), 0, stream>>>(Wo + (size_t)l * 589824, wt + lw + 1769472, 768, 768);
    transpose_bf16<<<dim3(96, 24), dim3(32, 8), 0, stream>>>(W1 + (size_t)l * 2359296, wt + lw + 2359296, 768, 3072);
    transpose_bf16<<<dim3(24, 96), dim3(32, 8), 0, stream>>>(W2 + (size_t)l * 2359296, wt + lw + 4718592, 3072, 768);
  }

  embed_ln<<<MM, 256, 0, stream>>>(ids, emb_tok, emb_pos, eg, eb, h32, hB);

  for (int l = 0; l < 2; l++) {
    const size_t lw = (size_t)l * 7077888;
    gemm_nt<1><<<dim3(18, 64), 256, 0, stream>>>(hB, wt + lw, bq + l * 768, bk + l * 768,
                                                 bv + l * 768, nullptr, qkvB,
                                                 MM, QKVN, 768);
    attn_win<<<dim3(SS / QB, 12, 2), 256, 0, stream>>>(qkvB, mask, ctxB);
    attn_r0_part<<<dim3(16, 12, 2), 256, 0, stream>>>(qkvB, mask, delta);
    attn_r0_comb<<<dim3(12, 2), 64, 0, stream>>>(delta, ctxB);
    gemm_nt<0><<<dim3(6, 64), 256, 0, stream>>>(ctxB, wt + lw + 1769472, bo + l * 768, nullptr,
                                                nullptr, delta, nullptr,
                                                MM, 768, 768);
    ln_res<<<MM, 256, 0, stream>>>(h32, delta, ln1g + l * 768, ln1b + l * 768, hB);
    gemm_nt<2><<<dim3(24, 64), 256, 0, stream>>>(hB, wt + lw + 2359296, b1 + l * 3072, nullptr,
                                                 nullptr, nullptr, f1B,
                                                 MM, 3072, 768);
    gemm_nt<0><<<dim3(6, 64), 256, 0, stream>>>(f1B, wt + lw + 4718592, b2 + l * 768, nullptr,
                                                nullptr, delta, nullptr,
                                                MM, 768, 3072);
    ln_res<<<MM, 256, 0, stream>>>(h32, delta, ln2g + l * 768, ln2b + l * 768, hB);
  }

  cls_head<<<dim3(BB), 256, 0, stream>>>(h32, clsW, clsb, out);
}

// Round 5
// 920.013 us; speedup vs baseline: 2.4943x; 1.0661x over previous
//
#include <hip/hip_runtime.h>
#include <math.h>

#define BB 2
#define SS 4096
#define DD 768
#define HH 12
#define LL 2
#define FF 3072
#define CC 256
#define MM 8192   // B*S
#define QB 128    // queries per attention block
#define QKVN 2304 // fused QKV row width

using frag8 = __attribute__((ext_vector_type(8))) short;   // 8 bf16
using f32x4 = __attribute__((ext_vector_type(4))) float;

// ---------- helpers ----------
__device__ __forceinline__ unsigned short f2b(float f) {
  unsigned u = __float_as_uint(f);
  u = u + 0x7fffu + ((u >> 16) & 1u);   // RNE
  return (unsigned short)(u >> 16);
}
__device__ __forceinline__ unsigned pack2(float a, float b) {
  return (unsigned)f2b(a) | ((unsigned)f2b(b) << 16);
}
__device__ __forceinline__ float b2f(unsigned short v) {
  return __uint_as_float(((unsigned)v) << 16);
}
__device__ __forceinline__ void unpack8(int4 t, float* f) {
  unsigned u;
  u = (unsigned)t.x; f[0] = __uint_as_float(u << 16); f[1] = __uint_as_float(u & 0xffff0000u);
  u = (unsigned)t.y; f[2] = __uint_as_float(u << 16); f[3] = __uint_as_float(u & 0xffff0000u);
  u = (unsigned)t.z; f[4] = __uint_as_float(u << 16); f[5] = __uint_as_float(u & 0xffff0000u);
  u = (unsigned)t.w; f[6] = __uint_as_float(u << 16); f[7] = __uint_as_float(u & 0xffff0000u);
}
__device__ __forceinline__ void reduce2(float& s1, float& s2) {
#pragma unroll
  for (int off = 32; off > 0; off >>= 1) {
    s1 += __shfl_down(s1, off);
    s2 += __shfl_down(s2, off);
  }
  __shared__ float r1[4], r2[4];
  const int lane = threadIdx.x & 63, wv = threadIdx.x >> 6;
  if (lane == 0) { r1[wv] = s1; r2[wv] = s2; }
  __syncthreads();
  s1 = r1[0] + r1[1] + r1[2] + r1[3];
  s2 = r2[0] + r2[1] + r2[2] + r2[3];
  __syncthreads();
}
// async global->LDS, 16B per lane; lds dest = wave-uniform base + lane*16
__device__ __forceinline__ void async16(const unsigned short* g, unsigned short* l) {
  __builtin_amdgcn_global_load_lds((__attribute__((address_space(1))) void*)(g),
                                   (__attribute__((address_space(3))) void*)(l), 16, 0, 0);
}

// ---------- batched weight transposes fp32(K,N) -> bf16(N,K) ----------
// 8 square 768x768 weights (Wq/Wk/Wv/Wo x 2 layers), z = l*4+w
__global__ __launch_bounds__(256) void transpose_sq8(const float* __restrict__ Wq,
                                                     const float* __restrict__ Wk,
                                                     const float* __restrict__ Wv,
                                                     const float* __restrict__ Wo,
                                                     unsigned short* __restrict__ wt) {
  __shared__ float t[32][33];
  const int z = blockIdx.z, l = z >> 2, w = z & 3;
  const float* in = ((w == 0) ? Wq : (w == 1) ? Wk : (w == 2) ? Wv : Wo) + (size_t)l * 589824;
  unsigned short* out = wt + (size_t)l * 7077888 + (size_t)w * 589824;
  const int n0 = blockIdx.x * 32, k0 = blockIdx.y * 32;
  const int tx = threadIdx.x, ty = threadIdx.y;   // block (32,8)
#pragma unroll
  for (int i = 0; i < 32; i += 8) t[ty + i][tx] = in[(size_t)(k0 + ty + i) * 768 + n0 + tx];
  __syncthreads();
#pragma unroll
  for (int i = 0; i < 32; i += 8) out[(size_t)(n0 + ty + i) * 768 + k0 + tx] = f2b(t[tx][ty + i]);
}

// generic, z-batched by strides
__global__ __launch_bounds__(256) void transpose_bz(const float* __restrict__ in0,
                                                    unsigned short* __restrict__ out0,
                                                    int K, int N, size_t sStride, size_t dStride) {
  __shared__ float t[32][33];
  const float* in = in0 + (size_t)blockIdx.z * sStride;
  unsigned short* out = out0 + (size_t)blockIdx.z * dStride;
  const int n0 = blockIdx.x * 32, k0 = blockIdx.y * 32;
  const int tx = threadIdx.x, ty = threadIdx.y;
#pragma unroll
  for (int i = 0; i < 32; i += 8) t[ty + i][tx] = in[(size_t)(k0 + ty + i) * N + n0 + tx];
  __syncthreads();
#pragma unroll
  for (int i = 0; i < 32; i += 8) out[(size_t)(n0 + ty + i) * K + k0 + tx] = f2b(t[tx][ty + i]);
}

// ---------- embedding + LN ----------
__global__ __launch_bounds__(256) void embed_ln(const int* __restrict__ ids,
                                                const float* __restrict__ etok,
                                                const float* __restrict__ epos,
                                                const float* __restrict__ g,
                                                const float* __restrict__ bb,
                                                float* __restrict__ h32,
                                                unsigned short* __restrict__ hB) {
  const int row = blockIdx.x;
  const int s = row & (SS - 1);
  const int id = ids[row];
  float x[3];
#pragma unroll
  for (int i = 0; i < 3; i++) {
    int j = threadIdx.x + i * 256;
    x[i] = etok[(size_t)id * DD + j] + epos[(size_t)s * DD + j];
  }
  float s1 = x[0] + x[1] + x[2];
  float s2 = x[0] * x[0] + x[1] * x[1] + x[2] * x[2];
  reduce2(s1, s2);
  const float mean = s1 * (1.f / 768.f);
  const float var = s2 * (1.f / 768.f) - mean * mean;
  const float rs = rsqrtf(var + 1e-5f);
#pragma unroll
  for (int i = 0; i < 3; i++) {
    int j = threadIdx.x + i * 256;
    float y = (x[i] - mean) * rs * g[j] + bb[j];
    h32[(size_t)row * DD + j] = y;
    hB[(size_t)row * DD + j] = f2b(y);
  }
}

// ---------- residual + LN (optionally two delta buffers: split-K partials) ----------
__global__ __launch_bounds__(256) void ln_res(float* __restrict__ h32,
                                              const float* __restrict__ delta,
                                              const float* __restrict__ delta2,
                                              const float* __restrict__ g,
                                              const float* __restrict__ bb,
                                              unsigned short* __restrict__ hB) {
  const int row = blockIdx.x;
  float x[3];
#pragma unroll
  for (int i = 0; i < 3; i++) {
    int j = threadIdx.x + i * 256;
    x[i] = h32[(size_t)row * DD + j] + delta[(size_t)row * DD + j];
  }
  if (delta2) {
#pragma unroll
    for (int i = 0; i < 3; i++) {
      int j = threadIdx.x + i * 256;
      x[i] += delta2[(size_t)row * DD + j];
    }
  }
  float s1 = x[0] + x[1] + x[2];
  float s2 = x[0] * x[0] + x[1] * x[1] + x[2] * x[2];
  reduce2(s1, s2);
  const float mean = s1 * (1.f / 768.f);
  const float var = s2 * (1.f / 768.f) - mean * mean;
  const float rs = rsqrtf(var + 1e-5f);
#pragma unroll
  for (int i = 0; i < 3; i++) {
    int j = threadIdx.x + i * 256;
    float y = (x[i] - mean) * rs * g[j] + bb[j];
    h32[(size_t)row * DD + j] = y;
    hB[(size_t)row * DD + j] = f2b(y);
  }
}

// ---------- bf16 MFMA GEMM:  C(M,N) = A(M,K) @ Bt(N,K)^T + bias ----------
// XCD-swizzled block mapping; optional split-K via gridDim.z (EPI0 only:
// z=0 -> outF (+bias), z=1 -> outF2 (no bias)).
// EPI 0: fp32 row-major
// EPI 1: QKV row-major bf16 [M][2304], q-segment scaled 0.125
// EPI 2: tanh-GELU -> bf16 row-major
template <int EPI>
__global__ __launch_bounds__(256) void gemm_nt(const unsigned short* __restrict__ A,
                                               const unsigned short* __restrict__ Bt,
                                               const float* __restrict__ bias0,
                                               const float* __restrict__ bias1,
                                               const float* __restrict__ bias2,
                                               float* __restrict__ outF,
                                               float* __restrict__ outF2,
                                               unsigned short* __restrict__ oq,
                                               int M, int N, int K) {
  __shared__ unsigned short sA[128 * 32];
  __shared__ unsigned short sB[128 * 32];
  const int tid = threadIdx.x;

  // XCD swizzle: blocks on one XCD (L%8) get consecutive slots; columns vary
  // fastest within a slot run -> one A row-panel per XCD resident in its L2.
  const int gx = gridDim.x;
  const int L = blockIdx.x + gx * blockIdx.y;
  const int slot = L >> 3;
  const int m0 = ((L & 7) + 8 * (slot / gx)) * 128;
  const int n0 = (slot % gx) * 128;

  // split-K
  const int kspan = K / gridDim.z;
  const int kbeg = blockIdx.z * kspan;

  const int wave = tid >> 6, lane = tid & 63;
  const int wm = (wave >> 1) * 64, wn = (wave & 1) * 64;
  const int quad = lane >> 4, r16 = lane & 15;

  // staging: wave w covers rows [w*32, w*32+32) in two 16-row issues
  const int srow = wave * 32 + (lane >> 2);
  const int scol = (lane & 3) * 8;
  const unsigned short* gA0 = A + (size_t)(m0 + srow) * K + kbeg + scol;
  const unsigned short* gA1 = gA0 + (size_t)16 * K;
  const unsigned short* gB0 = Bt + (size_t)(n0 + srow) * K + kbeg + scol;
  const unsigned short* gB1 = gB0 + (size_t)16 * K;
  unsigned short* lA0 = &sA[(wave * 32) * 32];
  unsigned short* lA1 = &sA[(wave * 32 + 16) * 32];
  unsigned short* lB0 = &sB[(wave * 32) * 32];
  unsigned short* lB1 = &sB[(wave * 32 + 16) * 32];

  f32x4 acc[4][4];
#pragma unroll
  for (int i = 0; i < 4; i++)
#pragma unroll
    for (int j = 0; j < 4; j++) acc[i][j] = (f32x4){0.f, 0.f, 0.f, 0.f};

  const int kiters = kspan >> 5;
  for (int kt = 0; kt < kiters; kt++) {
    const int k0 = kt << 5;
    __syncthreads();
    async16(gA0 + k0, lA0);
    async16(gA1 + k0, lA1);
    async16(gB0 + k0, lB0);
    async16(gB1 + k0, lB1);
    __syncthreads();   // drains vmcnt(0)
    frag8 af[4], bf[4];
#pragma unroll
    for (int i = 0; i < 4; i++)
      af[i] = *reinterpret_cast<const frag8*>(&sA[(wm + i * 16 + r16) * 32 + quad * 8]);
#pragma unroll
    for (int j = 0; j < 4; j++)
      bf[j] = *reinterpret_cast<const frag8*>(&sB[(wn + j * 16 + r16) * 32 + quad * 8]);
#pragma unroll
    for (int i = 0; i < 4; i++)
#pragma unroll
      for (int j = 0; j < 4; j++)
        acc[i][j] = __builtin_amdgcn_mfma_f32_16x16x32_bf16(af[i], bf[j], acc[i][j], 0, 0, 0);
  }

  // EPI1 block-uniform segment select (N=2304, 768 = 6 x 128-tiles)
  const int which = (EPI == 1) ? (n0 / 768) : 0;
  const float* bw = (EPI == 1) ? ((which == 0) ? bias0 : (which == 1) ? bias1 : bias2) : bias0;
  const float qsc = (EPI == 1 && which == 0) ? 0.125f : 1.f;
  const int cofs = which * 768;

  float* dst = (blockIdx.z == 0) ? outF : outF2;
  const bool addb = (blockIdx.z == 0);

#pragma unroll
  for (int i = 0; i < 4; i++)
#pragma unroll
    for (int j = 0; j < 4; j++)
#pragma unroll
      for (int rr = 0; rr < 4; rr++) {
        const int row = m0 + wm + i * 16 + quad * 4 + rr;
        const int col = n0 + wn + j * 16 + r16;
        if (EPI == 0) {
          dst[(size_t)row * N + col] = acc[i][j][rr] + (addb ? bias0[col] : 0.f);
        } else if (EPI == 1) {
          float v = (acc[i][j][rr] + bw[col - cofs]) * qsc;
          oq[(size_t)row * N + col] = f2b(v);
        } else {
          float v = acc[i][j][rr] + bias0[col];
          // tanh-GELU: v * sigmoid(2*0.7978845608*(v + 0.044715 v^3))
          float y = 1.5957691216f * (v + 0.044715f * v * v * v);
          float ge = v / (1.f + __expf(-y));
          oq[(size_t)row * N + col] = f2b(ge);
        }
      }
}

// ---------- MFMA flash sliding-window attention (transposed scores) ----------
// block = 256 thr (4 waves), handles QB=128 queries of (b,h); wave owns 32.
// S^T = K.Q^T  => C-layout: col(r16)=query, row(quad*4+rr)=key  => per-lane softmax state.
// O^T = V^T.P  => C-layout: col(r16)=query, row=d  => packed epilogue stores.
__global__ __launch_bounds__(256) void attn_win(const unsigned short* __restrict__ qkv,
                                                const int* __restrict__ mask,
                                                unsigned short* __restrict__ ctxB) {
  const int n = blockIdx.x, h = blockIdx.y, b = blockIdx.z;
  const int tid = threadIdx.x;
  const int wave = tid >> 6, lane = tid & 63;
  const int quad = lane >> 4, r16 = lane & 15;
  const size_t rowB = (size_t)(b * SS);

  __shared__ unsigned short sK[64 * 72];        // keys x d, stride 72
  __shared__ unsigned short sVt[64 * 72];       // d x keys, stride 72
  __shared__ unsigned short sP2[4][32 * 72];    // per-wave P^T: [q_local][key], stride 72
  __shared__ __align__(16) int sM[64];

  const int qw0 = n * QB + wave * 32;

  // Q fragments (B-operand): lane r16 -> q, quad*8+j -> d
  frag8 qf[2][2];
#pragma unroll
  for (int mt = 0; mt < 2; mt++)
#pragma unroll
    for (int kh = 0; kh < 2; kh++) {
      int4 t = *reinterpret_cast<const int4*>(
          qkv + (rowB + qw0 + mt * 16 + r16) * QKVN + h * 64 + kh * 32 + quad * 8);
      qf[mt][kh] = *reinterpret_cast<frag8*>(&t);
    }

  f32x4 oacc[4][2];   // [dt][mt]
#pragma unroll
  for (int dt = 0; dt < 4; dt++)
#pragma unroll
    for (int mt = 0; mt < 2; mt++) oacc[dt][mt] = (f32x4){0.f, 0.f, 0.f, 0.f};
  float mx[2], li[2];
#pragma unroll
  for (int mt = 0; mt < 2; mt++) { mx[mt] = -1e30f; li[mt] = 0.f; }

  const int kbase = n * QB - 256;
  for (int ch = -1; ch < 10; ch++) {
    const int kc = kbase + ch * 64;
    const bool isG = (ch < 0);
    __syncthreads();
    // ---- stage K (row-major) ----
    {
      const int key = tid >> 2, d0 = (tid & 3) * 16;
      const int kp = isG ? ((key == 0) ? 0 : -1) : kc + key;
      int4 a = make_int4(0, 0, 0, 0), c = make_int4(0, 0, 0, 0);
      if (kp >= 0 && kp < SS) {
        const unsigned short* src = qkv + (rowB + kp) * QKVN + 768 + h * 64 + d0;
        a = *reinterpret_cast<const int4*>(src);
        c = *reinterpret_cast<const int4*>(src + 8);
      }
      *reinterpret_cast<int4*>(&sK[key * 72 + d0]) = a;
      *reinterpret_cast<int4*>(&sK[key * 72 + d0 + 8]) = c;
    }
    // ---- stage V transposed ----
    {
      const int key = tid & 63, d0 = (tid >> 6) * 16;
      const int kp = isG ? ((key == 0) ? 0 : -1) : kc + key;
      int4 a = make_int4(0, 0, 0, 0), c = make_int4(0, 0, 0, 0);
      if (kp >= 0 && kp < SS) {
        const unsigned short* src = qkv + (rowB + kp) * QKVN + 1536 + h * 64 + d0;
        a = *reinterpret_cast<const int4*>(src);
        c = *reinterpret_cast<const int4*>(src + 8);
      }
      unsigned short e[16];
      *reinterpret_cast<int4*>(&e[0]) = a;
      *reinterpret_cast<int4*>(&e[8]) = c;
#pragma unroll
      for (int j = 0; j < 16; j++) sVt[(d0 + j) * 72 + key] = e[j];
    }
    if (tid < 64) {
      int ok;
      if (isG) ok = (tid == 0) ? mask[rowB] : 0;
      else {
        const int kp = kc + tid;
        ok = (kp >= 1 && kp < SS) ? mask[rowB + kp] : 0;
      }
      sM[tid] = ok;
    }
    __syncthreads();

    // wave band skip (compute only; barriers stay uniform)
    if (!isG && (kc > qw0 + 31 + 256 || kc + 63 < qw0 - 256)) continue;

    // ---- S^T = K.Q^T ----
    f32x4 sacc[4][2];   // [nt][mt]: row=key part, col=q
#pragma unroll
    for (int nt = 0; nt < 4; nt++)
#pragma unroll
      for (int mt = 0; mt < 2; mt++) sacc[nt][mt] = (f32x4){0.f, 0.f, 0.f, 0.f};
#pragma unroll
    for (int kh = 0; kh < 2; kh++) {
      frag8 kf[4];
#pragma unroll
      for (int nt = 0; nt < 4; nt++)
        kf[nt] = *reinterpret_cast<const frag8*>(&sK[(nt * 16 + r16) * 72 + kh * 32 + quad * 8]);
#pragma unroll
      for (int nt = 0; nt < 4; nt++)
#pragma unroll
        for (int mt = 0; mt < 2; mt++)
          sacc[nt][mt] = __builtin_amdgcn_mfma_f32_16x16x32_bf16(kf[nt], qf[mt][kh], sacc[nt][mt], 0, 0, 0);
    }

    // mask bits per key row (same for both mt)
    int mv[4][4];
#pragma unroll
    for (int nt = 0; nt < 4; nt++) {
      int4 t = *reinterpret_cast<const int4*>(&sM[nt * 16 + quad * 4]);
      mv[nt][0] = t.x; mv[nt][1] = t.y; mv[nt][2] = t.z; mv[nt][3] = t.w;
    }

    // ---- per-lane online softmax (q on r16) ----
#pragma unroll
    for (int mt = 0; mt < 2; mt++) {
      const int qg = qw0 + mt * 16 + r16;
      float m_c = -1e30f;
#pragma unroll
      for (int nt = 0; nt < 4; nt++)
#pragma unroll
        for (int rr = 0; rr < 4; rr++) {
          const int kp = kc + nt * 16 + quad * 4 + rr;
          const bool valid = (mv[nt][rr] != 0) && (isG || (unsigned)(kp - qg + 256) <= 512u);
          const float s = valid ? sacc[nt][mt][rr] : -1e30f;
          sacc[nt][mt][rr] = s;
          m_c = fmaxf(m_c, s);
        }
      m_c = fmaxf(m_c, __shfl_xor(m_c, 16, 64));
      m_c = fmaxf(m_c, __shfl_xor(m_c, 32, 64));
      const float mnew = fmaxf(mx[mt], m_c);
      const float alpha = __expf(mx[mt] - mnew);
      mx[mt] = mnew;
      float s_c = 0.f;
#pragma unroll
      for (int nt = 0; nt < 4; nt++) {
        float pk[4];
#pragma unroll
        for (int rr = 0; rr < 4; rr++) {
          const float sv = sacc[nt][mt][rr];
          float p = __expf(sv - mnew);
          p = (sv > -5e29f) ? p : 0.f;
          s_c += p;
          pk[rr] = p;
        }
        uint2 w;
        w.x = pack2(pk[0], pk[1]);
        w.y = pack2(pk[2], pk[3]);
        *reinterpret_cast<uint2*>(&sP2[wave][(mt * 16 + r16) * 72 + nt * 16 + quad * 4]) = w;
      }
      s_c += __shfl_xor(s_c, 16, 64);
      s_c += __shfl_xor(s_c, 32, 64);
      li[mt] = li[mt] * alpha + s_c;
#pragma unroll
      for (int dt = 0; dt < 4; dt++)
#pragma unroll
        for (int rr = 0; rr < 4; rr++) oacc[dt][mt][rr] *= alpha;
    }

    // ---- O^T += V^T.P (same-wave LDS, in-order) ----
#pragma unroll
    for (int kh = 0; kh < 2; kh++) {
      frag8 vf[4], pf[2];
#pragma unroll
      for (int dt = 0; dt < 4; dt++)
        vf[dt] = *reinterpret_cast<const frag8*>(&sVt[(dt * 16 + r16) * 72 + kh * 32 + quad * 8]);
#pragma unroll
      for (int mt = 0; mt < 2; mt++)
        pf[mt] = *reinterpret_cast<const frag8*>(&sP2[wave][(mt * 16 + r16) * 72 + kh * 32 + quad * 8]);
#pragma unroll
      for (int dt = 0; dt < 4; dt++)
#pragma unroll
        for (int mt = 0; mt < 2; mt++)
          oacc[dt][mt] = __builtin_amdgcn_mfma_f32_16x16x32_bf16(vf[dt], pf[mt], oacc[dt][mt], 0, 0, 0);
    }
  }

  // ---- epilogue: packed 8B stores ----
#pragma unroll
  for (int mt = 0; mt < 2; mt++) {
    const float inv = 1.f / li[mt];
    const int qg = qw0 + mt * 16 + r16;
#pragma unroll
    for (int dt = 0; dt < 4; dt++) {
      uint2 w;
      w.x = pack2(oacc[dt][mt][0] * inv, oacc[dt][mt][1] * inv);
      w.y = pack2(oacc[dt][mt][2] * inv, oacc[dt][mt][3] * inv);
      *reinterpret_cast<uint2*>(ctxB + (rowB + qg) * DD + h * 64 + dt * 16 + quad * 4) = w;
    }
  }
}

// ---------- full attention for query 0: split-K phase 1 ----------
__global__ __launch_bounds__(256) void attn_r0_part(const unsigned short* __restrict__ qkv,
                                                    const int* __restrict__ mask,
                                                    float* __restrict__ part) {
  const int ch = blockIdx.x, h = blockIdx.y, b = blockIdx.z;
  const int tid = threadIdx.x;
  const int lane = tid & 63, wave = tid >> 6;
  const size_t rowB = (size_t)(b * SS);

  __shared__ float sQ[64];
  __shared__ float wmx[4], wls[4];
  __shared__ float sPp[256];
  __shared__ float sO[4][64];
  if (tid < 8) {
    int4 t = *reinterpret_cast<const int4*>(qkv + rowB * QKVN + h * 64 + tid * 8);
    float f[8]; unpack8(t, f);
#pragma unroll
    for (int j = 0; j < 8; j++) sQ[tid * 8 + j] = f[j];
  }
  __syncthreads();

  const int key = ch * 256 + tid;
  float sc;
  {
    float s = 0.f;
    const unsigned short* kp = qkv + (rowB + key) * QKVN + 768 + h * 64;
#pragma unroll
    for (int i = 0; i < 8; i++) {
      int4 t = *reinterpret_cast<const int4*>(kp + i * 8);
      float f[8]; unpack8(t, f);
#pragma unroll
      for (int j = 0; j < 8; j++) s = fmaf(sQ[i * 8 + j], f[j], s);
    }
    sc = (mask[rowB + key] != 0) ? s : -1e9f;
  }
  float m = sc;
#pragma unroll
  for (int off = 1; off < 64; off <<= 1) m = fmaxf(m, __shfl_xor(m, off, 64));
  if (lane == 0) wmx[wave] = m;
  __syncthreads();
  const float Mx = fmaxf(fmaxf(wmx[0], wmx[1]), fmaxf(wmx[2], wmx[3]));
  const float p = __expf(sc - Mx);
  float ls = p;
#pragma unroll
  for (int off = 1; off < 64; off <<= 1) ls += __shfl_xor(ls, off, 64);
  sPp[tid] = p;
  if (lane == 0) wls[wave] = ls;
  __syncthreads();

  // per-wave matvec over its 64 keys; lane owns output dim d
  float acc = 0.f;
  const unsigned short* vb = qkv + (rowB + ch * 256 + wave * 64) * QKVN + 1536 + h * 64 + lane;
#pragma unroll 4
  for (int t = 0; t < 64; t++)
    acc = fmaf(sPp[wave * 64 + t], b2f(vb[(size_t)t * QKVN]), acc);
  sO[wave][lane] = acc;
  __syncthreads();
  if (tid < 64) {
    float* pp = part + ((size_t)((b * HH + h) * 16 + ch)) * 68;
    pp[tid] = sO[0][tid] + sO[1][tid] + sO[2][tid] + sO[3][tid];
    if (tid == 0) {
      pp[64] = Mx;
      pp[65] = wls[0] + wls[1] + wls[2] + wls[3];
    }
  }
}

// ---------- phase 2: combine 16 chunk partials, overwrite ctx row 0 ----------
__global__ __launch_bounds__(64) void attn_r0_comb(const float* __restrict__ part,
                                                   unsigned short* __restrict__ ctxB) {
  const int h = blockIdx.x, b = blockIdx.y;
  const int tid = threadIdx.x;
  const float* base = part + ((size_t)((b * HH + h) * 16)) * 68;
  float M = -1e30f;
#pragma unroll
  for (int c = 0; c < 16; c++) M = fmaxf(M, base[c * 68 + 64]);
  float L = 0.f, o = 0.f;
#pragma unroll
  for (int c = 0; c < 16; c++) {
    const float w = __expf(base[c * 68 + 64] - M);
    L += base[c * 68 + 65] * w;
    o = fmaf(w, base[c * 68 + tid], o);
  }
  ctxB[((size_t)(b * SS)) * DD + h * 64 + tid] = f2b(o / L);
}

// ---------- classifier ----------
__global__ __launch_bounds__(256) void cls_head(const float* __restrict__ h32,
                                                const float* __restrict__ W,
                                                const float* __restrict__ bc,
                                                float* __restrict__ out) {
  const int b = blockIdx.x;
  const float* hr = h32 + (size_t)b * SS * DD;
  float p0 = 0.f, p1 = 0.f, p2 = 0.f;
  for (int d = threadIdx.x; d < DD; d += 256) {
    const float x = hr[d];
    p0 = fmaf(x, W[d * 3 + 0], p0);
    p1 = fmaf(x, W[d * 3 + 1], p1);
    p2 = fmaf(x, W[d * 3 + 2], p2);
  }
  __shared__ float r0[256], r1[256], r2[256];
  r0[threadIdx.x] = p0; r1[threadIdx.x] = p1; r2[threadIdx.x] = p2;
  __syncthreads();
  if (threadIdx.x == 0) {
    float s0 = 0.f, s1 = 0.f, s2 = 0.f;
    for (int t = 0; t < 256; t++) { s0 += r0[t]; s1 += r1[t]; s2 += r2[t]; }
    out[b * 3 + 0] = s0 + bc[0];
    out[b * 3 + 1] = s1 + bc[1];
    out[b * 3 + 2] = s2 + bc[2];
  }
}

// ---------- workspace layout (bytes) ----------
static const size_t OFF_WT = 0;             // transposed weights, bf16
static const size_t OFF_H32 = 28311552;     // MM*DD fp32
static const size_t OFF_HB = 53477376;      // MM*DD bf16
static const size_t OFF_QKV = 66060288;     // MM*2304 bf16 (QKV; later split-K partial #2)
static const size_t OFF_CTX = 103809024;    // MM*DD bf16
static const size_t OFF_DELTA = 116391936;  // MM*DD fp32 (r0 partials; split-K partial #1)
static const size_t OFF_F1 = 141557760;     // MM*FF bf16
static const size_t WS_NEEDED = 191889408;

extern "C" void kernel_launch(void* const* d_in, const int* in_sizes, int n_in,
                              void* d_out, int out_size, void* d_ws, size_t ws_size,
                              hipStream_t stream) {
  (void)in_sizes; (void)n_in; (void)out_size;
  if (ws_size < WS_NEEDED) return;

  const int* ids = (const int*)d_in[0];
  const int* mask = (const int*)d_in[1];
  const float* emb_tok = (const float*)d_in[2];
  const float* emb_pos = (const float*)d_in[3];
  const float* eg = (const float*)d_in[4];
  const float* eb = (const float*)d_in[5];
  const float* Wq = (const float*)d_in[6];
  const float* bq = (const float*)d_in[7];
  const float* Wk = (const float*)d_in[8];
  const float* bk = (const float*)d_in[9];
  const float* Wv = (const float*)d_in[10];
  const float* bv = (const float*)d_in[11];
  const float* Wo = (const float*)d_in[12];
  const float* bo = (const float*)d_in[13];
  const float* ln1g = (const float*)d_in[14];
  const float* ln1b = (const float*)d_in[15];
  const float* W1 = (const float*)d_in[16];
  const float* b1 = (const float*)d_in[17];
  const float* W2 = (const float*)d_in[18];
  const float* b2 = (const float*)d_in[19];
  const float* ln2g = (const float*)d_in[20];
  const float* ln2b = (const float*)d_in[21];
  const float* clsW = (const float*)d_in[22];
  const float* clsb = (const float*)d_in[23];
  float* out = (float*)d_out;

  char* ws = (char*)d_ws;
  unsigned short* wt = (unsigned short*)(ws + OFF_WT);
  float* h32 = (float*)(ws + OFF_H32);
  unsigned short* hB = (unsigned short*)(ws + OFF_HB);
  unsigned short* qkvB = (unsigned short*)(ws + OFF_QKV);
  unsigned short* ctxB = (unsigned short*)(ws + OFF_CTX);
  float* delta = (float*)(ws + OFF_DELTA);
  float* aux = (float*)(ws + OFF_QKV);       // split-K partial #2 (QKV region dead by then)
  unsigned short* f1B = (unsigned short*)(ws + OFF_F1);

  // batched weight transposes: 3 dispatches total
  transpose_sq8<<<dim3(24, 24, 8), dim3(32, 8), 0, stream>>>(Wq, Wk, Wv, Wo, wt);
  transpose_bz<<<dim3(96, 24, 2), dim3(32, 8), 0, stream>>>(W1, wt + 2359296, 768, 3072,
                                                            2359296, 7077888);
  transpose_bz<<<dim3(24, 96, 2), dim3(32, 8), 0, stream>>>(W2, wt + 4718592, 3072, 768,
                                                            2359296, 7077888);

  embed_ln<<<MM, 256, 0, stream>>>(ids, emb_tok, emb_pos, eg, eb, h32, hB);

  for (int l = 0; l < 2; l++) {
    const size_t lw = (size_t)l * 7077888;
    gemm_nt<1><<<dim3(18, 64), 256, 0, stream>>>(hB, wt + lw, bq + l * 768, bk + l * 768,
                                                 bv + l * 768, nullptr, nullptr, qkvB,
                                                 MM, QKVN, 768);
    attn_win<<<dim3(SS / QB, 12, 2), 256, 0, stream>>>(qkvB, mask, ctxB);
    attn_r0_part<<<dim3(16, 12, 2), 256, 0, stream>>>(qkvB, mask, delta);
    attn_r0_comb<<<dim3(12, 2), 64, 0, stream>>>(delta, ctxB);
    // Wo: split-K=2 (z=0 -> delta (+bias), z=1 -> aux)
    gemm_nt<0><<<dim3(6, 64, 2), 256, 0, stream>>>(ctxB, wt + lw + 1769472, bo + l * 768,
                                                   nullptr, nullptr, delta, aux, nullptr,
                                                   MM, 768, 768);
    ln_res<<<MM, 256, 0, stream>>>(h32, delta, aux, ln1g + l * 768, ln1b + l * 768, hB);
    gemm_nt<2><<<dim3(24, 64), 256, 0, stream>>>(hB, wt + lw + 2359296, b1 + l * 3072,
                                                 nullptr, nullptr, nullptr, nullptr, f1B,
                                                 MM, 3072, 768);
    // FFN2: split-K=2
    gemm_nt<0><<<dim3(6, 64, 2), 256, 0, stream>>>(f1B, wt + lw + 4718592, b2 + l * 768,
                                                   nullptr, nullptr, delta, aux, nullptr,
                                                   MM, 768, 3072);
    ln_res<<<MM, 256, 0, stream>>>(h32, delta, aux, ln2g + l * 768, ln2b + l * 768, hB);
  }

  cls_head<<<dim3(BB), 256, 0, stream>>>(h32, clsW, clsb, out);
}